// Round 9
// baseline (331.878 us; speedup 1.0000x reference)
//
#include <hip/hip_runtime.h>
#include <cmath>

typedef __bf16 bf16x8 __attribute__((ext_vector_type(8)));
typedef float  f32x4  __attribute__((ext_vector_type(4)));
typedef float  f32x2  __attribute__((ext_vector_type(2)));

#define B_  8
#define L_  1024
#define DM  256
#define DI  512
#define DS  16
#define DTR 16
#define M_  (B_*L_)
#define NC  64     // scan chunks
#define CT  16     // steps per chunk

__device__ inline float softplus_f(float z){
  return (z > 20.f) ? z : __logf(1.f + __expf(z));
}
__device__ inline float silu_f(float z){
  return z / (1.f + __expf(-z));
}

// powers e1^(n+1), n=0..15, via depth-4 tree
__device__ inline void pow_tree(float e1, float* p){
  float e2=e1*e1, e4=e2*e2, e8=e4*e4;
  float e3=e2*e1, e5=e4*e1, e6=e4*e2, e7=e4*e3;
  p[0]=e1;  p[1]=e2;  p[2]=e3;  p[3]=e4;
  p[4]=e5;  p[5]=e6;  p[6]=e7;  p[7]=e8;
  p[8]=e8*e1;  p[9]=e8*e2;  p[10]=e8*e3;  p[11]=e8*e4;
  p[12]=e8*e5; p[13]=e8*e6; p[14]=e8*e7;  p[15]=e8*e8;
}

// ---------------- dtype probe: are inputs fp32 or bf16? ----------------
__global__ __launch_bounds__(256) void probe_k(const void* x, int* flag){
  __shared__ int sbad[256];
  int tid = threadIdx.x;
  const unsigned short* u = (const unsigned short*)x;
  int bad = 0;
  for (int i = tid; i < 4096; i += 256){
    unsigned short v = u[2*i];
    int e = (v >> 7) & 0xFF;
    if (e >= 160 || e < 96) bad++;
  }
  sbad[tid] = bad;
  __syncthreads();
  if (tid == 0){
    int t = 0;
    for (int i=0;i<256;i++) t += sbad[i];
    *flag = (t > 1024) ? 1 : 0;   // 1 = inputs are fp32
  }
}

// ---------------- convert small vectors to canonical bf16 ----------------
struct CvtJob { const void* src; __bf16* dst; int n; };
struct CvtArgs { CvtJob j[11]; };

__global__ __launch_bounds__(256) void cvt_k(CvtArgs a, const int* flag){
  int e = blockIdx.x*256 + threadIdx.x;
  const int f = *flag;
  #pragma unroll 1
  for (int jj=0; jj<11; jj++){
    int n = a.j[jj].n;
    if (e < n){
      if (f) a.j[jj].dst[e] = (__bf16)(((const float*)a.j[jj].src)[e]);
      else   a.j[jj].dst[e] = ((const __bf16*)a.j[jj].src)[e];
      return;
    }
    e -= n;
  }
}

// exact-f32 copy of ALog (both dirs)
__global__ __launch_bounds__(256) void cvtA_k(const void* a0, const void* a1,
                                              float* o0, float* o1, const int* flag){
  int gid = blockIdx.x*256 + threadIdx.x;   // 16384
  const int f = *flag;
  const void* src = (gid < 8192) ? a0 : a1;
  float* dst = (gid < 8192) ? o0 : o1;
  int i = gid & 8191;
  dst[i] = f ? ((const float*)src)[i] : (float)((const __bf16*)src)[i];
}

// ---------------- prep: transpose weights, reading RAW inputs per flag ----------------
struct PrepJob { const void* src; void* dst; int rows; int cols; int f32out; };
struct PrepArgs { PrepJob j[11]; };

__global__ __launch_bounds__(256) void prep_k(PrepArgs a, const int* flag){
  int e = blockIdx.x*256 + threadIdx.x;
  const int f = *flag;
  #pragma unroll 1
  for (int jj=0; jj<11; jj++){
    int sz = a.j[jj].rows * a.j[jj].cols;
    if (e < sz){
      int cols = a.j[jj].cols;
      int r = e / cols, c = e - r*cols;
      float v = f ? ((const float*)a.j[jj].src)[e] : (float)((const __bf16*)a.j[jj].src)[e];
      if (a.j[jj].f32out) ((float*)a.j[jj].dst)[c*a.j[jj].rows + r] = v;
      else ((__bf16*)a.j[jj].dst)[(long)c*a.j[jj].rows + r] = (__bf16)v;
      return;
    }
    e -= sz;
  }
}

// ---------------- LayerNorm (raw x per flag) ----------------
__global__ __launch_bounds__(256) void ln_k(const void* x, const __bf16* g,
                                            const __bf16* bb, __bf16* xn, const int* flag){
  const int row = blockIdx.x;
  const int d = threadIdx.x;
  const int f = *flag;
  long idx = (long)row*DM + d;
  float v = f ? ((const float*)x)[idx] : (float)(((const __bf16*)x)[idx]);
  float s = v, q = v*v;
  #pragma unroll
  for (int off=32; off>0; off>>=1){
    s += __shfl_down(s, off);
    q += __shfl_down(q, off);
  }
  __shared__ float ss[4], sq[4];
  int w = d >> 6, ln = d & 63;
  if (ln == 0){ ss[w] = s; sq[w] = q; }
  __syncthreads();
  s = ss[0]+ss[1]+ss[2]+ss[3];
  q = sq[0]+sq[1]+sq[2]+sq[3];
  float mu  = s * (1.f/DM);
  float var = q * (1.f/DM) - mu*mu;
  float xnv = (v - mu) * rsqrtf(var + 1e-5f) * (float)g[d] + (float)bb[d];
  xn[idx] = (__bf16)xnv;
}

// ---------------- generic MFMA GEMM: C[M][N] = A[M][K] * Bt[N][K]^T ----------------
// KK = compile-time K (full unroll + 1-stage register prefetch).
// EPI 0: split store (c<DI -> C [xz], c>=DI -> res via bias ptr); A rows flipped when dir==1
// EPI 1: f32 store
// EPI 2: bf16 store into concat buffer colOff=dir*DM
// EPI 3: store + bias + RAW residual (dtype per *outflag); output dtype per *outflag
template<int WMT,int WNT,int BWM,int BWN,int EPI,int KK>
__global__ __launch_bounds__(64*BWM*BWN) void gemm_k(
    const __bf16* A0, const __bf16* A1,
    const __bf16* B0, const __bf16* B1,
    void* C0, void* C1,
    int lda, int ldb, int ldc,
    const __bf16* bias, const void* resid, const int* outflag)
{
  const int dir = blockIdx.z;
  const __bf16* A  = dir ? A1 : A0;
  const __bf16* Bt = dir ? B1 : B0;
  char* C = (char*)(dir ? C1 : C0);
  __bf16* resW = (EPI==0) ? (__bf16*)(dir ? resid : (const void*)bias) : nullptr;
  const int tid  = threadIdx.x;
  const int lane = tid & 63;
  const int wid  = tid >> 6;
  const int wm = wid % BWM;
  const int wn = wid / BWM;
  const int mBase = (blockIdx.x*BWM + wm) * (WMT*16);
  const int nBase = (blockIdx.y*BWN + wn) * (WNT*16);
  const int lm = lane & 15;
  const int kq = (lane >> 4) * 8;
  const int of = (EPI==3 && outflag) ? *outflag : 0;

  long aoff[WMT];
  #pragma unroll
  for (int i=0;i<WMT;i++){
    int r = mBase + i*16 + lm;
    if (EPI==0 && dir==1){ int b = r >> 10, t = r & (L_-1); r = (b<<10) + (L_-1-t); }
    aoff[i] = (long)r * lda + kq;
  }
  long boff[WNT];
  #pragma unroll
  for (int j=0;j<WNT;j++) boff[j] = (long)(nBase + j*16 + lm) * ldb + kq;

  // 1-stage register prefetch pipeline over fully-unrolled K
  bf16x8 afn[WMT], bfn[WNT];
  #pragma unroll
  for (int i=0;i<WMT;i++) afn[i] = *(const bf16x8*)(A  + aoff[i]);
  #pragma unroll
  for (int j=0;j<WNT;j++) bfn[j] = *(const bf16x8*)(Bt + boff[j]);

  f32x4 acc[WMT][WNT] = {};
  #pragma unroll
  for (int k0=0; k0<KK; k0+=32){
    bf16x8 af[WMT], bfr[WNT];
    #pragma unroll
    for (int i=0;i<WMT;i++) af[i]  = afn[i];
    #pragma unroll
    for (int j=0;j<WNT;j++) bfr[j] = bfn[j];
    if (k0 + 32 < KK){
      #pragma unroll
      for (int i=0;i<WMT;i++) afn[i] = *(const bf16x8*)(A  + aoff[i] + k0 + 32);
      #pragma unroll
      for (int j=0;j<WNT;j++) bfn[j] = *(const bf16x8*)(Bt + boff[j] + k0 + 32);
    }
    #pragma unroll
    for (int i=0;i<WMT;i++)
      #pragma unroll
      for (int j=0;j<WNT;j++)
        acc[i][j] = __builtin_amdgcn_mfma_f32_16x16x32_bf16(af[i], bfr[j], acc[i][j], 0,0,0);
  }

  const int coff = (EPI==2) ? dir*DM : 0;
  #pragma unroll
  for (int i=0;i<WMT;i++){
    #pragma unroll
    for (int rr=0;rr<4;rr++){
      int r = mBase + i*16 + (lane>>4)*4 + rr;
      int rOut = r;
      if (EPI==2 && dir==1){ int b = r >> 10, t = r & (L_-1); rOut = (b<<10) + (L_-1-t); }
      #pragma unroll
      for (int j=0;j<WNT;j++){
        int c = nBase + j*16 + lm;
        float v = acc[i][j][rr];
        if (EPI==0){
          if (c < DI) ((__bf16*)C)[(long)r*DI + c] = (__bf16)v;
          else        resW[(long)r*DI + (c-DI)]    = (__bf16)v;
        } else if (EPI==3){
          float rsd = of ? ((const float*)resid)[(long)r*DM + c]
                         : (float)((const __bf16*)resid)[(long)r*DM + c];
          v += (float)bias[c] + rsd;
          if (of) ((float*)C)[(long)r*ldc + c] = v;
          else    ((__bf16*)C)[(long)r*ldc + c] = (__bf16)v;
        } else if (EPI==1){
          ((float*)C)[(long)r*ldc + c] = v;
        } else {
          ((__bf16*)C)[(long)rOut*ldc + coff + c] = (__bf16)v;
        }
      }
    }
  }
}

// ---------------- causal depthwise conv (DC=4) + SiLU ----------------
__global__ __launch_bounds__(256) void conv_k(
    const __bf16* xz0, const __bf16* xz1,
    const float* cw0, const float* cw1,
    const __bf16* cb0, const __bf16* cb1,
    __bf16* xs0, __bf16* xs1)
{
  const int dir = blockIdx.z;
  const __bf16* xz = dir ? xz1 : xz0;
  const float*  cw = dir ? cw1 : cw0;
  const __bf16* cb = dir ? cb1 : cb0;
  __bf16* xs = dir ? xs1 : xs0;

  int gid = blockIdx.x*256 + threadIdx.x;
  int c8 = gid & 63;
  int t  = (gid >> 6) & (L_-1);
  int b  = gid >> 16;
  int cbase = c8*8;

  float acc[8];
  bf16x8 bb = *(const bf16x8*)(cb + cbase);
  #pragma unroll
  for (int c=0;c<8;c++) acc[c] = (float)bb[c];
  #pragma unroll
  for (int j=0;j<4;j++){
    int tj = t - 3 + j;
    if (tj >= 0){
      bf16x8 xv = *(const bf16x8*)(xz + ((long)(b*L_ + tj))*DI + cbase);
      #pragma unroll
      for (int c=0;c<8;c++) acc[c] += (float)xv[c] * cw[j*DI + cbase + c];
    }
  }
  bf16x8 outv;
  #pragma unroll
  for (int c=0;c<8;c++) outv[c] = (__bf16)silu_f(acc[c]);
  *(bf16x8*)(xs + ((long)(b*L_ + t))*DI + cbase) = outv;
}

// ============ dt-proj: delta[M][DI] = softplus(dlt @ dtW + dtB) ============
__global__ __launch_bounds__(256) void dt_k(
    const float* xd0, const float* xd1,
    const float* dw0, const float* dw1,
    const __bf16* dtB0, const __bf16* dtB1,
    float* dg0, float* dg1)
{
  const int dir = blockIdx.z;
  const float*  xd  = dir ? xd1 : xd0;
  const float*  dw  = dir ? dw1 : dw0;
  const __bf16* dtB = dir ? dtB1 : dtB0;
  float* dg = dir ? dg1 : dg0;
  const long row0 = (long)blockIdx.x * 32;
  const int tid = threadIdx.x;

  __shared__ float sdlt[32][16];
  { int e = tid*2; int r = e>>4, q = e&15;
    *(f32x2*)&sdlt[r][q] = *(const f32x2*)(xd + (row0+r)*48 + q); }

  const int d0 = tid, d1 = tid + 256;
  float dwa[16], dwb[16];
  { const f32x4* p = (const f32x4*)(dw + d0*DTR);
    #pragma unroll
    for (int q=0;q<4;q++){ f32x4 v=p[q]; dwa[q*4]=v[0]; dwa[q*4+1]=v[1]; dwa[q*4+2]=v[2]; dwa[q*4+3]=v[3]; } }
  { const f32x4* p = (const f32x4*)(dw + d1*DTR);
    #pragma unroll
    for (int q=0;q<4;q++){ f32x4 v=p[q]; dwb[q*4]=v[0]; dwb[q*4+1]=v[1]; dwb[q*4+2]=v[2]; dwb[q*4+3]=v[3]; } }
  const float b0v = (float)dtB[d0];
  const float b1v = (float)dtB[d1];
  __syncthreads();

  #pragma unroll 4
  for (int r=0;r<32;r++){
    f32x4 q0 = *(const f32x4*)&sdlt[r][0];
    f32x4 q1 = *(const f32x4*)&sdlt[r][4];
    f32x4 q2 = *(const f32x4*)&sdlt[r][8];
    f32x4 q3 = *(const f32x4*)&sdlt[r][12];
    float z0 = b0v, z1 = b1v;
    z0 += q0[0]*dwa[0]+q0[1]*dwa[1]+q0[2]*dwa[2]+q0[3]*dwa[3];
    z0 += q1[0]*dwa[4]+q1[1]*dwa[5]+q1[2]*dwa[6]+q1[3]*dwa[7];
    z0 += q2[0]*dwa[8]+q2[1]*dwa[9]+q2[2]*dwa[10]+q2[3]*dwa[11];
    z0 += q3[0]*dwa[12]+q3[1]*dwa[13]+q3[2]*dwa[14]+q3[3]*dwa[15];
    z1 += q0[0]*dwb[0]+q0[1]*dwb[1]+q0[2]*dwb[2]+q0[3]*dwb[3];
    z1 += q1[0]*dwb[4]+q1[1]*dwb[5]+q1[2]*dwb[6]+q1[3]*dwb[7];
    z1 += q2[0]*dwb[8]+q2[1]*dwb[9]+q2[2]*dwb[10]+q2[3]*dwb[11];
    z1 += q3[0]*dwb[12]+q3[1]*dwb[13]+q3[2]*dwb[14]+q3[3]*dwb[15];
    dg[(row0+r)*DI + d0] = softplus_f(z0);
    dg[(row0+r)*DI + d1] = softplus_f(z1);
  }
}

// ============ scan phase A: lean local scan + chunk summaries ============
__global__ __launch_bounds__(256) void scanA_k(
    const float* xd0, const float* xd1,
    const __bf16* xs0, const __bf16* xs1,
    const float* dg0, const float* dg1,
    const float* ALf0, const float* ALf1,
    float* hend, float* sumd)
{
  const int dir = blockIdx.z;
  const float*  xd  = dir ? xd1 : xd0;
  const __bf16* xs  = dir ? xs1 : xs0;
  const float*  dg  = dir ? dg1 : dg0;
  const float*  ALf = dir ? ALf1 : ALf0;

  const int b   = blockIdx.y;
  const int c   = blockIdx.x >> 1;
  const int dg_ = blockIdx.x & 1;
  const int tid = threadIdx.x;
  const int d   = dg_*256 + tid;
  const int db  = dir*8 + b;
  const long row0 = (long)b*L_ + c*CT;

  __shared__ float sB[CT][16];
  if (tid < CT*4){ int e = tid*4; int t = e>>4, n = e&15;
    *(f32x4*)&sB[t][n] = *(const f32x4*)(xd + (row0+t)*48 + 16 + n); }

  float A[16];
  { const f32x4* p = (const f32x4*)(ALf + d*DS);
    #pragma unroll
    for (int q=0;q<4;q++){ f32x4 v=p[q];
      A[q*4]=-__expf(v[0]); A[q*4+1]=-__expf(v[1]); A[q*4+2]=-__expf(v[2]); A[q*4+3]=-__expf(v[3]); } }
  bool pow_ok = true;
  #pragma unroll
  for (int n=0;n<16;n++) pow_ok = pow_ok && (fabsf(A[n] + (float)(n+1)) < 0.003f*(n+1));

  float h[16];
  #pragma unroll
  for (int n=0;n<16;n++) h[n]=0.f;
  float sdelta = 0.f;
  __syncthreads();

  if (pow_ok){
    #pragma unroll 2
    for (int t=0;t<CT;t++){
      long row = row0 + t;
      f32x4 b0 = *(const f32x4*)&sB[t][0];
      f32x4 b1 = *(const f32x4*)&sB[t][4];
      f32x4 b2 = *(const f32x4*)&sB[t][8];
      f32x4 b3 = *(const f32x4*)&sB[t][12];
      float delta = dg[row*DI + d];
      sdelta += delta;
      float xv = (float)xs[row*DI + d];
      float dx = delta*xv;
      float pw[16];
      pow_tree(__expf(-delta), pw);
      float Bv[16] = {b0[0],b0[1],b0[2],b0[3], b1[0],b1[1],b1[2],b1[3],
                      b2[0],b2[1],b2[2],b2[3], b3[0],b3[1],b3[2],b3[3]};
      #pragma unroll
      for (int n=0;n<16;n++)
        h[n] = pw[n]*h[n] + dx*Bv[n];
    }
  } else {
    #pragma unroll 2
    for (int t=0;t<CT;t++){
      long row = row0 + t;
      f32x4 b0 = *(const f32x4*)&sB[t][0];
      f32x4 b1 = *(const f32x4*)&sB[t][4];
      f32x4 b2 = *(const f32x4*)&sB[t][8];
      f32x4 b3 = *(const f32x4*)&sB[t][12];
      float delta = dg[row*DI + d];
      sdelta += delta;
      float xv = (float)xs[row*DI + d];
      float dx = delta*xv;
      float Bv[16] = {b0[0],b0[1],b0[2],b0[3], b1[0],b1[1],b1[2],b1[3],
                      b2[0],b2[1],b2[2],b2[3], b3[0],b3[1],b3[2],b3[3]};
      #pragma unroll
      for (int n=0;n<16;n++)
        h[n] = __expf(delta*A[n])*h[n] + dx*Bv[n];
    }
  }

  long hb = (((long)db*NC + c)*DI + d)*16;
  f32x4* hp = (f32x4*)(hend + hb);
  #pragma unroll
  for (int q=0;q<4;q++){ f32x4 v; v[0]=h[q*4]; v[1]=h[q*4+1]; v[2]=h[q*4+2]; v[3]=h[q*4+3]; hp[q]=v; }
  sumd[((long)db*NC + c)*DI + d] = sdelta;
}

// ============ phase B: chain chunk summaries sequentially ============
__global__ __launch_bounds__(256) void scanB_k(
    const float* ALf0, const float* ALf1,
    const float* hend, const float* sumd, float* Hbuf)
{
  int gid = blockIdx.x*256 + threadIdx.x;   // 131072
  int n  = gid & 15;
  int d  = (gid>>4) & 511;
  int db = gid >> 13;
  const float* ALf = (db>=8) ? ALf1 : ALf0;
  float A_dn = -__expf(ALf[d*DS + n]);
  float H = 0.f;
  #pragma unroll 1
  for (int c=0;c<NC;c++){
    long base = (((long)db*NC + c)*DI + d)*16 + n;
    Hbuf[base] = H;
    float S = sumd[((long)db*NC + c)*DI + d];
    H = hend[base] + __expf(A_dn*S)*H;
  }
}

// ============ phase C: re-scan seeded from Hbuf; y + gate; in-place into res ============
__global__ __launch_bounds__(256) void scanC_k(
    const float* xd0, const float* xd1,
    const __bf16* xs0, const __bf16* xs1,
    __bf16* res0, __bf16* res1,
    const float* dg0, const float* dg1,
    const float* ALf0, const float* ALf1,
    const __bf16* Dp0, const __bf16* Dp1,
    const float* Hbuf)
{
  const int dir = blockIdx.z;
  const float*  xd  = dir ? xd1 : xd0;
  const __bf16* xs  = dir ? xs1 : xs0;
  __bf16*       res = dir ? res1 : res0;
  const float*  dg  = dir ? dg1 : dg0;
  const float*  ALf = dir ? ALf1 : ALf0;
  const __bf16* Dp  = dir ? Dp1 : Dp0;

  const int b   = blockIdx.y;
  const int c   = blockIdx.x >> 1;
  const int dg_ = blockIdx.x & 1;
  const int tid = threadIdx.x;
  const int d   = dg_*256 + tid;
  const int db  = dir*8 + b;
  const long row0 = (long)b*L_ + c*CT;

  __shared__ float sBC[CT][32];
  if (tid < CT*8){ int e = tid*4; int t = e>>5, cc = e&31;
    *(f32x4*)&sBC[t][cc] = *(const f32x4*)(xd + (row0+t)*48 + 16 + cc); }

  float A[16];
  { const f32x4* p = (const f32x4*)(ALf + d*DS);
    #pragma unroll
    for (int q=0;q<4;q++){ f32x4 v=p[q];
      A[q*4]=-__expf(v[0]); A[q*4+1]=-__expf(v[1]); A[q*4+2]=-__expf(v[2]); A[q*4+3]=-__expf(v[3]); } }
  bool pow_ok = true;
  #pragma unroll
  for (int n=0;n<16;n++) pow_ok = pow_ok && (fabsf(A[n] + (float)(n+1)) < 0.003f*(n+1));

  float h[16];
  { long hb = (((long)db*NC + c)*DI + d)*16;
    const f32x4* p = (const f32x4*)(Hbuf + hb);
    #pragma unroll
    for (int q=0;q<4;q++){ f32x4 v = p[q]; h[q*4]=v[0]; h[q*4+1]=v[1]; h[q*4+2]=v[2]; h[q*4+3]=v[3]; } }
  const float Dpv = (float)Dp[d];
  __syncthreads();

  if (pow_ok){
    #pragma unroll 2
    for (int t=0;t<CT;t++){
      long row = row0 + t;
      f32x4 b0 = *(const f32x4*)&sBC[t][0];
      f32x4 b1 = *(const f32x4*)&sBC[t][4];
      f32x4 b2 = *(const f32x4*)&sBC[t][8];
      f32x4 b3 = *(const f32x4*)&sBC[t][12];
      f32x4 c0 = *(const f32x4*)&sBC[t][16];
      f32x4 c1 = *(const f32x4*)&sBC[t][20];
      f32x4 c2 = *(const f32x4*)&sBC[t][24];
      f32x4 c3 = *(const f32x4*)&sBC[t][28];
      float delta = dg[row*DI + d];
      float xv = (float)xs[row*DI + d];
      float dx = delta*xv;
      float pw[16];
      pow_tree(__expf(-delta), pw);
      float Bv[16] = {b0[0],b0[1],b0[2],b0[3], b1[0],b1[1],b1[2],b1[3],
                      b2[0],b2[1],b2[2],b2[3], b3[0],b3[1],b3[2],b3[3]};
      float Cv[16] = {c0[0],c0[1],c0[2],c0[3], c1[0],c1[1],c1[2],c1[3],
                      c2[0],c2[1],c2[2],c2[3], c3[0],c3[1],c3[2],c3[3]};
      float p = 0.f;
      #pragma unroll
      for (int n=0;n<16;n++){
        h[n] = pw[n]*h[n] + dx*Bv[n];
        p += h[n]*Cv[n];
      }
      float yv = p + Dpv*xv;
      float rv = (float)res[row*DI + d];
      res[row*DI + d] = (__bf16)(yv * silu_f(rv));
    }
  } else {
    #pragma unroll 2
    for (int t=0;t<CT;t++){
      long row = row0 + t;
      f32x4 b0 = *(const f32x4*)&sBC[t][0];
      f32x4 b1 = *(const f32x4*)&sBC[t][4];
      f32x4 b2 = *(const f32x4*)&sBC[t][8];
      f32x4 b3 = *(const f32x4*)&sBC[t][12];
      f32x4 c0 = *(const f32x4*)&sBC[t][16];
      f32x4 c1 = *(const f32x4*)&sBC[t][20];
      f32x4 c2 = *(const f32x4*)&sBC[t][24];
      f32x4 c3 = *(const f32x4*)&sBC[t][28];
      float delta = dg[row*DI + d];
      float xv = (float)xs[row*DI + d];
      float dx = delta*xv;
      float Bv[16] = {b0[0],b0[1],b0[2],b0[3], b1[0],b1[1],b1[2],b1[3],
                      b2[0],b2[1],b2[2],b2[3], b3[0],b3[1],b3[2],b3[3]};
      float Cv[16] = {c0[0],c0[1],c0[2],c0[3], c1[0],c1[1],c1[2],c1[3],
                      c2[0],c2[1],c2[2],c2[3], c3[0],c3[1],c3[2],c3[3]};
      float p = 0.f;
      #pragma unroll
      for (int n=0;n<16;n++){
        h[n] = __expf(delta*A[n])*h[n] + dx*Bv[n];
        p += h[n]*Cv[n];
      }
      float yv = p + Dpv*xv;
      float rv = (float)res[row*DI + d];
      res[row*DI + d] = (__bf16)(yv * silu_f(rv));
    }
  }
}

// ---------------- FALLBACK scan ----------------
__global__ __launch_bounds__(256) void scan_k(
    const float* xd0, const float* xd1,
    const __bf16* xs0, const __bf16* xs1,
    __bf16* res0, __bf16* res1,
    const float* dw0, const float* dw1,
    const __bf16* dtB0, const __bf16* dtB1,
    const __bf16* AL0, const __bf16* AL1,
    const __bf16* Dp0, const __bf16* Dp1)
{
  const int dir = blockIdx.z;
  const float*  xd  = dir ? xd1 : xd0;
  const __bf16* xs  = dir ? xs1 : xs0;
  __bf16*       res = dir ? res1 : res0;
  const float*  dw  = dir ? dw1 : dw0;
  const __bf16* dtB = dir ? dtB1 : dtB0;
  const __bf16* AL  = dir ? AL1 : AL0;
  const __bf16* Dp  = dir ? Dp1 : Dp0;

  const int b  = blockIdx.y;
  const int dt = blockIdx.x;
  const int tid = threadIdx.x;
  const int n  = tid & 15;
  const int dl = tid >> 4;
  const int d  = dt*16 + dl;

  __shared__ float sxd[128][48];
  __shared__ float sx[128][16];
  __shared__ float sdelta[128][16];
  __shared__ float sy[128][16];
  __shared__ float sdw[16][17];
  __shared__ float sdb[16];

  sdw[dl][n] = dw[(dt*16+dl)*DTR + n];
  if (tid < 16) sdb[tid] = (float)dtB[dt*16 + tid];
  const float A_dn = -__expf((float)AL[d*DS + n]);
  float h = 0.f;
  __syncthreads();

  const long rowB = (long)b * L_;
  for (int c0=0; c0<L_; c0+=128){
    #pragma unroll 1
    for (int k=0;k<24;k++){
      int e = tid + k*256;
      int t = e / 48, col = e - t*48;
      sxd[t][col] = xd[(rowB + c0 + t)*48 + col];
    }
    #pragma unroll 1
    for (int k=0;k<8;k++){
      int e = tid + k*256;
      int t = e >> 4, dc = e & 15;
      sx[t][dc] = (float)xs[(rowB + c0 + t)*DI + dt*16 + dc];
    }
    __syncthreads();
    #pragma unroll 1
    for (int k=0;k<8;k++){
      int e = tid + k*256;
      int t = e >> 4, dc = e & 15;
      float z = sdb[dc];
      #pragma unroll
      for (int q=0;q<16;q++) z += sxd[t][q] * sdw[dc][q];
      sdelta[t][dc] = softplus_f(z);
    }
    __syncthreads();
    #pragma unroll 2
    for (int tt=0;tt<128;tt++){
      float delta = sdelta[tt][dl];
      float xv = sx[tt][dl];
      float Bv = sxd[tt][16+n];
      float Cv = sxd[tt][32+n];
      float dA = __expf(delta * A_dn);
      h = dA*h + (delta*xv)*Bv;
      float p = h * Cv;
      p += __shfl_xor(p, 1);
      p += __shfl_xor(p, 2);
      p += __shfl_xor(p, 4);
      p += __shfl_xor(p, 8);
      if (n == 0) sy[tt][dl] = p;
    }
    __syncthreads();
    #pragma unroll 1
    for (int k=0;k<8;k++){
      int e = tid + k*256;
      int t = e >> 4, dc = e & 15;
      long row = rowB + c0 + t;
      float yv = sy[t][dc] + (float)Dp[dt*16+dc] * sx[t][dc];
      float rv = (float)res[row*DI + dt*16 + dc];
      res[row*DI + dt*16 + dc] = (__bf16)(yv * silu_f(rv));
    }
    __syncthreads();
  }
}

// ---------------- launch ----------------
extern "C" void kernel_launch(void* const* d_in, const int* in_sizes, int n_in,
                              void* d_out, int out_size, void* d_ws, size_t ws_size,
                              hipStream_t stream)
{
  const size_t MB = 1u<<20;
  if (ws_size < 61*MB) return;
  const bool newscan = (ws_size >= 160*MB);

  char* w = (char*)d_ws;
  __bf16* xz[2]  = {(__bf16*)(w + 0),      (__bf16*)(w + 8*MB)};
  __bf16* res[2] = {(__bf16*)(w + 16*MB),  (__bf16*)(w + 24*MB)};
  __bf16* xsc[2] = {(__bf16*)(w + 32*MB),  (__bf16*)(w + 40*MB)};
  __bf16* xn     = (__bf16*)(w + 48*MB);
  float*  xdbl[2]= {(float*)(w + 48*MB),   (float*)(w + 48*MB + (size_t)M_*48*4)};
  __bf16* fusedIn = xsc[0];

  char* wp = w + 52*MB;
  auto carve = [&](size_t bytes)->void*{
    void* p = wp;
    wp += (bytes + 255) & ~(size_t)255;
    return p;
  };
  __bf16 *inWt[2], *xWt[2], *outWt[2];
  float *dtWt[2], *convWt[2];
  for (int m=0;m<2;m++){
    inWt[m]   = (__bf16*)carve((size_t)(2*DI)*DM*2);
    xWt[m]    = (__bf16*)carve((size_t)48*DI*2);
    outWt[m]  = (__bf16*)carve((size_t)DM*DI*2);
    dtWt[m]   = (float*)carve((size_t)DI*DTR*4);
    convWt[m] = (float*)carve((size_t)4*DI*4);
  }
  __bf16* fusWt = (__bf16*)carve((size_t)DM*DI*2);
  int* flag = (int*)carve(256);
  float* ALf[2] = {(float*)carve((size_t)DI*DS*4), (float*)carve((size_t)DI*DS*4)};

  char* cp = w + 55*MB;
  auto carve2 = [&](size_t elems)->__bf16*{
    __bf16* p = (__bf16*)cp;
    cp += (elems*2 + 255) & ~(size_t)255;
    return p;
  };
  __bf16* ngc = carve2(DM);
  __bf16* nbc = carve2(DM);
  __bf16 *convBc[2], *dtBc[2], *ALc[2], *Dpc[2];
  for (int m=0;m<2;m++){
    convBc[m] = carve2(DI);
    dtBc[m]   = carve2(DI);
    ALc[m]    = carve2((size_t)DI*DS);
    Dpc[m]    = carve2(DI);
  }
  __bf16* fusBc = carve2(DM);

  float* dgA[2] = {(float*)(w + 56*MB), (float*)(w + 72*MB)};
  float* hend = (float*)(w + 88*MB);
  float* sumd = (float*)(w + 122*MB);
  float* Hbuf = (float*)(w + 125*MB);

  probe_k<<<1, 256, 0, stream>>>(d_in[0], flag);

  CvtArgs ca;
  int ci = 0;
  ca.j[ci++] = {d_in[1],  ngc, DM};
  ca.j[ci++] = {d_in[2],  nbc, DM};
  for (int m=0;m<2;m++){
    int base = 3 + m*9;
    ca.j[ci++] = {d_in[base+2], convBc[m], DI};
    ca.j[ci++] = {d_in[base+5], dtBc[m],   DI};
    ca.j[ci++] = {d_in[base+6], ALc[m],    DI*DS};
    ca.j[ci++] = {d_in[base+7], Dpc[m],    DI};
  }
  ca.j[ci++] = {d_in[22], fusBc, DM};
  cvt_k<<<79, 256, 0, stream>>>(ca, flag);
  cvtA_k<<<64, 256, 0, stream>>>(d_in[9], d_in[18], ALf[0], ALf[1], flag);

  PrepArgs pa;
  int ji = 0;
  for (int m=0;m<2;m++){
    int base = 3 + m*9;
    pa.j[ji++] = {d_in[base+0], inWt[m],  DM,  2*DI, 0};
    pa.j[ji++] = {d_in[base+3], xWt[m],   DI,  48,   0};
    pa.j[ji++] = {d_in[base+8], outWt[m], DI,  DM,   0};
    pa.j[ji++] = {d_in[base+4], dtWt[m],  DTR, DI,   1};
    pa.j[ji++] = {d_in[base+1], convWt[m],DI,  4,    1};
  }
  pa.j[ji++] = {d_in[21], fusWt, DI, DM, 0};
  prep_k<<<(987136+255)/256, 256, 0, stream>>>(pa, flag);

  ln_k<<<M_, 256, 0, stream>>>(d_in[0], ngc, nbc, xn, flag);
  gemm_k<4,4,2,2,0,256><<<dim3(M_/128, (2*DI)/128, 2), 256, 0, stream>>>(
      xn, xn, inWt[0], inWt[1], xz[0], xz[1], DM, DM, DI, res[0], res[1], nullptr);
  conv_k<<<dim3((M_*64)/256, 1, 2), 256, 0, stream>>>(
      xz[0], xz[1], convWt[0], convWt[1], convBc[0], convBc[1], xsc[0], xsc[1]);
  gemm_k<1,3,4,1,1,512><<<dim3(M_/64, 1, 2), 256, 0, stream>>>(
      xsc[0], xsc[1], xWt[0], xWt[1], xdbl[0], xdbl[1], DI, DI, 48, nullptr, nullptr, nullptr);

  if (newscan){
    dt_k<<<dim3(M_/32, 1, 2), 256, 0, stream>>>(
        xdbl[0], xdbl[1], dtWt[0], dtWt[1], dtBc[0], dtBc[1], dgA[0], dgA[1]);
    scanA_k<<<dim3(NC*2, B_, 2), 256, 0, stream>>>(
        xdbl[0], xdbl[1], xsc[0], xsc[1], dgA[0], dgA[1], ALf[0], ALf[1], hend, sumd);
    scanB_k<<<131072/256, 256, 0, stream>>>(ALf[0], ALf[1], hend, sumd, Hbuf);
    scanC_k<<<dim3(NC*2, B_, 2), 256, 0, stream>>>(
        xdbl[0], xdbl[1], xsc[0], xsc[1], res[0], res[1],
        dgA[0], dgA[1], ALf[0], ALf[1], Dpc[0], Dpc[1], Hbuf);
  } else {
    scan_k<<<dim3(DI/16, B_, 2), 256, 0, stream>>>(
        xdbl[0], xdbl[1], xsc[0], xsc[1], res[0], res[1], dtWt[0], dtWt[1],
        dtBc[0], dtBc[1], ALc[0], ALc[1], Dpc[0], Dpc[1]);
  }

  gemm_k<4,2,2,2,2,512><<<dim3(M_/128, DM/64, 2), 256, 0, stream>>>(
      res[0], res[1], outWt[0], outWt[1], fusedIn, fusedIn, DI, DI, 2*DM, nullptr, nullptr, nullptr);
  gemm_k<4,2,2,2,3,512><<<dim3(M_/128, DM/64, 1), 256, 0, stream>>>(
      fusedIn, fusedIn, fusWt, fusWt, d_out, d_out, 2*DM, 2*DM, DM, fusBc, d_in[0], flag);
}

// Round 10
// 286.305 us; speedup vs baseline: 1.1592x; 1.1592x over previous
//
#include <hip/hip_runtime.h>
#include <cmath>

typedef __bf16 bf16x8 __attribute__((ext_vector_type(8)));
typedef float  f32x4  __attribute__((ext_vector_type(4)));
typedef float  f32x2  __attribute__((ext_vector_type(2)));

#define B_  8
#define L_  1024
#define DM  256
#define DI  512
#define DS  16
#define DTR 16
#define M_  (B_*L_)
#define NC  64     // scan chunks
#define CT  16     // steps per chunk

__device__ inline float softplus_f(float z){
  return (z > 20.f) ? z : __logf(1.f + __expf(z));
}
__device__ inline float silu_f(float z){
  return z / (1.f + __expf(-z));
}

// powers e1^(n+1), n=0..15, via depth-4 tree
__device__ inline void pow_tree(float e1, float* p){
  float e2=e1*e1, e4=e2*e2, e8=e4*e4;
  float e3=e2*e1, e5=e4*e1, e6=e4*e2, e7=e4*e3;
  p[0]=e1;  p[1]=e2;  p[2]=e3;  p[3]=e4;
  p[4]=e5;  p[5]=e6;  p[6]=e7;  p[7]=e8;
  p[8]=e8*e1;  p[9]=e8*e2;  p[10]=e8*e3;  p[11]=e8*e4;
  p[12]=e8*e5; p[13]=e8*e6; p[14]=e8*e7;  p[15]=e8*e8;
}

// ---------------- dtype probe ----------------
__global__ __launch_bounds__(256) void probe_k(const void* x, int* flag){
  __shared__ int sbad[256];
  int tid = threadIdx.x;
  const unsigned short* u = (const unsigned short*)x;
  int bad = 0;
  for (int i = tid; i < 4096; i += 256){
    unsigned short v = u[2*i];
    int e = (v >> 7) & 0xFF;
    if (e >= 160 || e < 96) bad++;
  }
  sbad[tid] = bad;
  __syncthreads();
  if (tid == 0){
    int t = 0;
    for (int i=0;i<256;i++) t += sbad[i];
    *flag = (t > 1024) ? 1 : 0;
  }
}

// ---------------- convert small vectors ----------------
struct CvtJob { const void* src; __bf16* dst; int n; };
struct CvtArgs { CvtJob j[11]; };

__global__ __launch_bounds__(256) void cvt_k(CvtArgs a, const int* flag){
  int e = blockIdx.x*256 + threadIdx.x;
  const int f = *flag;
  #pragma unroll 1
  for (int jj=0; jj<11; jj++){
    int n = a.j[jj].n;
    if (e < n){
      if (f) a.j[jj].dst[e] = (__bf16)(((const float*)a.j[jj].src)[e]);
      else   a.j[jj].dst[e] = ((const __bf16*)a.j[jj].src)[e];
      return;
    }
    e -= n;
  }
}

__global__ __launch_bounds__(256) void cvtA_k(const void* a0, const void* a1,
                                              float* o0, float* o1, const int* flag){
  int gid = blockIdx.x*256 + threadIdx.x;
  const int f = *flag;
  const void* src = (gid < 8192) ? a0 : a1;
  float* dst = (gid < 8192) ? o0 : o1;
  int i = gid & 8191;
  dst[i] = f ? ((const float*)src)[i] : (float)((const __bf16*)src)[i];
}

// ---------------- prep: transpose weights (raw per flag) ----------------
struct PrepJob { const void* src; void* dst; int rows; int cols; int f32out; };
struct PrepArgs { PrepJob j[11]; };

__global__ __launch_bounds__(256) void prep_k(PrepArgs a, const int* flag){
  int e = blockIdx.x*256 + threadIdx.x;
  const int f = *flag;
  #pragma unroll 1
  for (int jj=0; jj<11; jj++){
    int sz = a.j[jj].rows * a.j[jj].cols;
    if (e < sz){
      int cols = a.j[jj].cols;
      int r = e / cols, c = e - r*cols;
      float v = f ? ((const float*)a.j[jj].src)[e] : (float)((const __bf16*)a.j[jj].src)[e];
      if (a.j[jj].f32out) ((float*)a.j[jj].dst)[c*a.j[jj].rows + r] = v;
      else ((__bf16*)a.j[jj].dst)[(long)c*a.j[jj].rows + r] = (__bf16)v;
      return;
    }
    e -= sz;
  }
}

// ---------------- LayerNorm ----------------
__global__ __launch_bounds__(256) void ln_k(const void* x, const __bf16* g,
                                            const __bf16* bb, __bf16* xn, const int* flag){
  const int row = blockIdx.x;
  const int d = threadIdx.x;
  const int f = *flag;
  long idx = (long)row*DM + d;
  float v = f ? ((const float*)x)[idx] : (float)(((const __bf16*)x)[idx]);
  float s = v, q = v*v;
  #pragma unroll
  for (int off=32; off>0; off>>=1){
    s += __shfl_down(s, off);
    q += __shfl_down(q, off);
  }
  __shared__ float ss[4], sq[4];
  int w = d >> 6, ln = d & 63;
  if (ln == 0){ ss[w] = s; sq[w] = q; }
  __syncthreads();
  s = ss[0]+ss[1]+ss[2]+ss[3];
  q = sq[0]+sq[1]+sq[2]+sq[3];
  float mu  = s * (1.f/DM);
  float var = q * (1.f/DM) - mu*mu;
  float xnv = (v - mu) * rsqrtf(var + 1e-5f) * (float)g[d] + (float)bb[d];
  xn[idx] = (__bf16)xnv;
}

// ============ LDS-staged MFMA GEMM (m97 pattern, global_load_lds width=16) ============
// C[M][N] = A[M][K] * Bt[N][K]^T.  BK=32, 256 threads = 2x2 waves.
// EPI 0: split store (c<DI->C, c>=DI->res via bias ptr); A rows time-flipped when dir==1
// EPI 2: bf16 store into concat buffer colOff=dir*DM; C rows time-flipped when dir==1
// EPI 3: store + bias + RAW residual; output dtype per *outflag
template<int BM,int BN,int EPI,int KK>
__global__ __launch_bounds__(256) void gemm_lds_k(
    const __bf16* A0, const __bf16* A1,
    const __bf16* B0, const __bf16* B1,
    void* C0, void* C1,
    int lda, int ldb, int ldc,
    const __bf16* bias, const void* resid, const int* outflag)
{
  constexpr int TM = BM/2, TN = BN/2;        // wave tile
  constexpr int WMT = TM/16, WNT = TN/16;
  constexpr int LA = BM/64, LB = BN/64;      // 16B loads per thread per tile

  const int dir = blockIdx.z;
  const __bf16* A  = dir ? A1 : A0;
  const __bf16* Bt = dir ? B1 : B0;
  char* C = (char*)(dir ? C1 : C0);
  __bf16* resW = (EPI==0) ? (__bf16*)(dir ? resid : (const void*)bias) : nullptr;
  const int tid  = threadIdx.x;
  const int lane = tid & 63;
  const int wid  = tid >> 6;
  const int wm = wid & 1;
  const int wn = wid >> 1;
  const int mBase = blockIdx.x * BM;
  const int nBase = blockIdx.y * BN;
  const int lm = lane & 15;
  const int kq = (lane >> 4) * 8;
  const int of = (EPI==3 && outflag) ? *outflag : 0;

  __shared__ __bf16 As[BM*32];
  __shared__ __bf16 Bs[BN*32];

  const __bf16* aS[LA];
  const __bf16* bS[LB];
  {
    int colk = (tid & 3) * 8;
    #pragma unroll
    for (int ld=0; ld<LA; ld++){
      int r = mBase + ld*64 + (tid >> 2);
      if (EPI==0 && dir==1){ int b = r >> 10, t = r & (L_-1); r = (b<<10) + (L_-1-t); }
      aS[ld] = A + (long)r*lda + colk;
    }
    #pragma unroll
    for (int ld=0; ld<LB; ld++){
      int r = nBase + ld*64 + (tid >> 2);
      bS[ld] = Bt + (long)r*ldb + colk;
    }
  }

  f32x4 acc[WMT][WNT] = {};
  for (int k0=0; k0<KK; k0+=32){
    #pragma unroll
    for (int ld=0; ld<LA; ld++)
      __builtin_amdgcn_global_load_lds(
        (const __attribute__((address_space(1))) void*)(aS[ld] + k0),
        (__attribute__((address_space(3))) void*)(&As[ld*2048 + tid*8]), 16, 0, 0);
    #pragma unroll
    for (int ld=0; ld<LB; ld++)
      __builtin_amdgcn_global_load_lds(
        (const __attribute__((address_space(1))) void*)(bS[ld] + k0),
        (__attribute__((address_space(3))) void*)(&Bs[ld*2048 + tid*8]), 16, 0, 0);
    __syncthreads();   // drains vmcnt -> LDS valid for all waves
    bf16x8 af[WMT], bfr[WNT];
    #pragma unroll
    for (int i=0;i<WMT;i++) af[i]  = *(const bf16x8*)&As[(wm*TM + i*16 + lm)*32 + kq];
    #pragma unroll
    for (int j=0;j<WNT;j++) bfr[j] = *(const bf16x8*)&Bs[(wn*TN + j*16 + lm)*32 + kq];
    #pragma unroll
    for (int i=0;i<WMT;i++)
      #pragma unroll
      for (int j=0;j<WNT;j++)
        acc[i][j] = __builtin_amdgcn_mfma_f32_16x16x32_bf16(af[i], bfr[j], acc[i][j], 0,0,0);
    __syncthreads();   // all reads done before next overwrite
  }

  const int coff = (EPI==2) ? dir*DM : 0;
  #pragma unroll
  for (int i=0;i<WMT;i++){
    #pragma unroll
    for (int rr=0;rr<4;rr++){
      int r = mBase + wm*TM + i*16 + (lane>>4)*4 + rr;
      int rOut = r;
      if (EPI==2 && dir==1){ int b = r >> 10, t = r & (L_-1); rOut = (b<<10) + (L_-1-t); }
      #pragma unroll
      for (int j=0;j<WNT;j++){
        int c = nBase + wn*TN + j*16 + lm;
        float v = acc[i][j][rr];
        if (EPI==0){
          if (c < DI) ((__bf16*)C)[(long)r*DI + c] = (__bf16)v;
          else        resW[(long)r*DI + (c-DI)]    = (__bf16)v;
        } else if (EPI==3){
          float rsd = of ? ((const float*)resid)[(long)r*DM + c]
                         : (float)((const __bf16*)resid)[(long)r*DM + c];
          v += (float)bias[c] + rsd;
          if (of) ((float*)C)[(long)r*ldc + c] = v;
          else    ((__bf16*)C)[(long)r*ldc + c] = (__bf16)v;
        } else {
          ((__bf16*)C)[(long)rOut*ldc + coff + c] = (__bf16)v;
        }
      }
    }
  }
}

// ---------------- register GEMM (kept for x-proj, N=48, EPI1=f32 store) ----------------
template<int WMT,int WNT,int BWM,int BWN,int KK>
__global__ __launch_bounds__(64*BWM*BWN) void gemm_r_k(
    const __bf16* A0, const __bf16* A1,
    const __bf16* B0, const __bf16* B1,
    float* C0, float* C1,
    int lda, int ldb, int ldc)
{
  const int dir = blockIdx.z;
  const __bf16* A  = dir ? A1 : A0;
  const __bf16* Bt = dir ? B1 : B0;
  float* C = dir ? C1 : C0;
  const int tid  = threadIdx.x;
  const int lane = tid & 63;
  const int wid  = tid >> 6;
  const int wm = wid % BWM;
  const int wn = wid / BWM;
  const int mBase = (blockIdx.x*BWM + wm) * (WMT*16);
  const int nBase = (blockIdx.y*BWN + wn) * (WNT*16);
  const int lm = lane & 15;
  const int kq = (lane >> 4) * 8;

  long aoff[WMT];
  #pragma unroll
  for (int i=0;i<WMT;i++) aoff[i] = (long)(mBase + i*16 + lm) * lda + kq;
  long boff[WNT];
  #pragma unroll
  for (int j=0;j<WNT;j++) boff[j] = (long)(nBase + j*16 + lm) * ldb + kq;

  f32x4 acc[WMT][WNT] = {};
  #pragma unroll
  for (int k0=0; k0<KK; k0+=32){
    bf16x8 af[WMT], bfr[WNT];
    #pragma unroll
    for (int i=0;i<WMT;i++) af[i]  = *(const bf16x8*)(A  + aoff[i] + k0);
    #pragma unroll
    for (int j=0;j<WNT;j++) bfr[j] = *(const bf16x8*)(Bt + boff[j] + k0);
    #pragma unroll
    for (int i=0;i<WMT;i++)
      #pragma unroll
      for (int j=0;j<WNT;j++)
        acc[i][j] = __builtin_amdgcn_mfma_f32_16x16x32_bf16(af[i], bfr[j], acc[i][j], 0,0,0);
  }

  #pragma unroll
  for (int i=0;i<WMT;i++)
    #pragma unroll
    for (int rr=0;rr<4;rr++){
      int r = mBase + i*16 + (lane>>4)*4 + rr;
      #pragma unroll
      for (int j=0;j<WNT;j++){
        int c = nBase + j*16 + lm;
        C[(long)r*ldc + c] = acc[i][j][rr];
      }
    }
}

// ---------------- causal depthwise conv (DC=4) + SiLU ----------------
__global__ __launch_bounds__(256) void conv_k(
    const __bf16* xz0, const __bf16* xz1,
    const float* cw0, const float* cw1,
    const __bf16* cb0, const __bf16* cb1,
    __bf16* xs0, __bf16* xs1)
{
  const int dir = blockIdx.z;
  const __bf16* xz = dir ? xz1 : xz0;
  const float*  cw = dir ? cw1 : cw0;
  const __bf16* cb = dir ? cb1 : cb0;
  __bf16* xs = dir ? xs1 : xs0;

  int gid = blockIdx.x*256 + threadIdx.x;
  int c8 = gid & 63;
  int t  = (gid >> 6) & (L_-1);
  int b  = gid >> 16;
  int cbase = c8*8;

  float acc[8];
  bf16x8 bb = *(const bf16x8*)(cb + cbase);
  #pragma unroll
  for (int c=0;c<8;c++) acc[c] = (float)bb[c];
  #pragma unroll
  for (int j=0;j<4;j++){
    int tj = t - 3 + j;
    if (tj >= 0){
      bf16x8 xv = *(const bf16x8*)(xz + ((long)(b*L_ + tj))*DI + cbase);
      #pragma unroll
      for (int c=0;c<8;c++) acc[c] += (float)xv[c] * cw[j*DI + cbase + c];
    }
  }
  bf16x8 outv;
  #pragma unroll
  for (int c=0;c<8;c++) outv[c] = (__bf16)silu_f(acc[c]);
  *(bf16x8*)(xs + ((long)(b*L_ + t))*DI + cbase) = outv;
}

// ============ dt-proj ============
__global__ __launch_bounds__(256) void dt_k(
    const float* xd0, const float* xd1,
    const float* dw0, const float* dw1,
    const __bf16* dtB0, const __bf16* dtB1,
    float* dg0, float* dg1)
{
  const int dir = blockIdx.z;
  const float*  xd  = dir ? xd1 : xd0;
  const float*  dw  = dir ? dw1 : dw0;
  const __bf16* dtB = dir ? dtB1 : dtB0;
  float* dg = dir ? dg1 : dg0;
  const long row0 = (long)blockIdx.x * 32;
  const int tid = threadIdx.x;

  __shared__ float sdlt[32][16];
  { int e = tid*2; int r = e>>4, q = e&15;
    *(f32x2*)&sdlt[r][q] = *(const f32x2*)(xd + (row0+r)*48 + q); }

  const int d0 = tid, d1 = tid + 256;
  float dwa[16], dwb[16];
  { const f32x4* p = (const f32x4*)(dw + d0*DTR);
    #pragma unroll
    for (int q=0;q<4;q++){ f32x4 v=p[q]; dwa[q*4]=v[0]; dwa[q*4+1]=v[1]; dwa[q*4+2]=v[2]; dwa[q*4+3]=v[3]; } }
  { const f32x4* p = (const f32x4*)(dw + d1*DTR);
    #pragma unroll
    for (int q=0;q<4;q++){ f32x4 v=p[q]; dwb[q*4]=v[0]; dwb[q*4+1]=v[1]; dwb[q*4+2]=v[2]; dwb[q*4+3]=v[3]; } }
  const float b0v = (float)dtB[d0];
  const float b1v = (float)dtB[d1];
  __syncthreads();

  #pragma unroll 4
  for (int r=0;r<32;r++){
    f32x4 q0 = *(const f32x4*)&sdlt[r][0];
    f32x4 q1 = *(const f32x4*)&sdlt[r][4];
    f32x4 q2 = *(const f32x4*)&sdlt[r][8];
    f32x4 q3 = *(const f32x4*)&sdlt[r][12];
    float z0 = b0v, z1 = b1v;
    z0 += q0[0]*dwa[0]+q0[1]*dwa[1]+q0[2]*dwa[2]+q0[3]*dwa[3];
    z0 += q1[0]*dwa[4]+q1[1]*dwa[5]+q1[2]*dwa[6]+q1[3]*dwa[7];
    z0 += q2[0]*dwa[8]+q2[1]*dwa[9]+q2[2]*dwa[10]+q2[3]*dwa[11];
    z0 += q3[0]*dwa[12]+q3[1]*dwa[13]+q3[2]*dwa[14]+q3[3]*dwa[15];
    z1 += q0[0]*dwb[0]+q0[1]*dwb[1]+q0[2]*dwb[2]+q0[3]*dwb[3];
    z1 += q1[0]*dwb[4]+q1[1]*dwb[5]+q1[2]*dwb[6]+q1[3]*dwb[7];
    z1 += q2[0]*dwb[8]+q2[1]*dwb[9]+q2[2]*dwb[10]+q2[3]*dwb[11];
    z1 += q3[0]*dwb[12]+q3[1]*dwb[13]+q3[2]*dwb[14]+q3[3]*dwb[15];
    dg[(row0+r)*DI + d0] = softplus_f(z0);
    dg[(row0+r)*DI + d1] = softplus_f(z1);
  }
}

// ============ scan phase A ============
__global__ __launch_bounds__(256) void scanA_k(
    const float* xd0, const float* xd1,
    const __bf16* xs0, const __bf16* xs1,
    const float* dg0, const float* dg1,
    const float* ALf0, const float* ALf1,
    float* hend, float* sumd)
{
  const int dir = blockIdx.z;
  const float*  xd  = dir ? xd1 : xd0;
  const __bf16* xs  = dir ? xs1 : xs0;
  const float*  dg  = dir ? dg1 : dg0;
  const float*  ALf = dir ? ALf1 : ALf0;

  const int b   = blockIdx.y;
  const int c   = blockIdx.x >> 1;
  const int dg_ = blockIdx.x & 1;
  const int tid = threadIdx.x;
  const int d   = dg_*256 + tid;
  const int db  = dir*8 + b;
  const long row0 = (long)b*L_ + c*CT;

  __shared__ float sB[CT][16];
  if (tid < CT*4){ int e = tid*4; int t = e>>4, n = e&15;
    *(f32x4*)&sB[t][n] = *(const f32x4*)(xd + (row0+t)*48 + 16 + n); }

  float A[16];
  { const f32x4* p = (const f32x4*)(ALf + d*DS);
    #pragma unroll
    for (int q=0;q<4;q++){ f32x4 v=p[q];
      A[q*4]=-__expf(v[0]); A[q*4+1]=-__expf(v[1]); A[q*4+2]=-__expf(v[2]); A[q*4+3]=-__expf(v[3]); } }
  bool pow_ok = true;
  #pragma unroll
  for (int n=0;n<16;n++) pow_ok = pow_ok && (fabsf(A[n] + (float)(n+1)) < 0.003f*(n+1));

  float h[16];
  #pragma unroll
  for (int n=0;n<16;n++) h[n]=0.f;
  float sdelta = 0.f;
  __syncthreads();

  if (pow_ok){
    #pragma unroll 2
    for (int t=0;t<CT;t++){
      long row = row0 + t;
      f32x4 b0 = *(const f32x4*)&sB[t][0];
      f32x4 b1 = *(const f32x4*)&sB[t][4];
      f32x4 b2 = *(const f32x4*)&sB[t][8];
      f32x4 b3 = *(const f32x4*)&sB[t][12];
      float delta = dg[row*DI + d];
      sdelta += delta;
      float xv = (float)xs[row*DI + d];
      float dx = delta*xv;
      float pw[16];
      pow_tree(__expf(-delta), pw);
      float Bv[16] = {b0[0],b0[1],b0[2],b0[3], b1[0],b1[1],b1[2],b1[3],
                      b2[0],b2[1],b2[2],b2[3], b3[0],b3[1],b3[2],b3[3]};
      #pragma unroll
      for (int n=0;n<16;n++)
        h[n] = pw[n]*h[n] + dx*Bv[n];
    }
  } else {
    #pragma unroll 2
    for (int t=0;t<CT;t++){
      long row = row0 + t;
      f32x4 b0 = *(const f32x4*)&sB[t][0];
      f32x4 b1 = *(const f32x4*)&sB[t][4];
      f32x4 b2 = *(const f32x4*)&sB[t][8];
      f32x4 b3 = *(const f32x4*)&sB[t][12];
      float delta = dg[row*DI + d];
      sdelta += delta;
      float xv = (float)xs[row*DI + d];
      float dx = delta*xv;
      float Bv[16] = {b0[0],b0[1],b0[2],b0[3], b1[0],b1[1],b1[2],b1[3],
                      b2[0],b2[1],b2[2],b2[3], b3[0],b3[1],b3[2],b3[3]};
      #pragma unroll
      for (int n=0;n<16;n++)
        h[n] = __expf(delta*A[n])*h[n] + dx*Bv[n];
    }
  }

  long hb = (((long)db*NC + c)*DI + d)*16;
  f32x4* hp = (f32x4*)(hend + hb);
  #pragma unroll
  for (int q=0;q<4;q++){ f32x4 v; v[0]=h[q*4]; v[1]=h[q*4+1]; v[2]=h[q*4+2]; v[3]=h[q*4+3]; hp[q]=v; }
  sumd[((long)db*NC + c)*DI + d] = sdelta;
}

// ============ phase B ============
__global__ __launch_bounds__(256) void scanB_k(
    const float* ALf0, const float* ALf1,
    const float* hend, const float* sumd, float* Hbuf)
{
  int gid = blockIdx.x*256 + threadIdx.x;
  int n  = gid & 15;
  int d  = (gid>>4) & 511;
  int db = gid >> 13;
  const float* ALf = (db>=8) ? ALf1 : ALf0;
  float A_dn = -__expf(ALf[d*DS + n]);
  float H = 0.f;
  #pragma unroll 1
  for (int c=0;c<NC;c++){
    long base = (((long)db*NC + c)*DI + d)*16 + n;
    Hbuf[base] = H;
    float S = sumd[((long)db*NC + c)*DI + d];
    H = hend[base] + __expf(A_dn*S)*H;
  }
}

// ============ phase C ============
__global__ __launch_bounds__(256) void scanC_k(
    const float* xd0, const float* xd1,
    const __bf16* xs0, const __bf16* xs1,
    __bf16* res0, __bf16* res1,
    const float* dg0, const float* dg1,
    const float* ALf0, const float* ALf1,
    const __bf16* Dp0, const __bf16* Dp1,
    const float* Hbuf)
{
  const int dir = blockIdx.z;
  const float*  xd  = dir ? xd1 : xd0;
  const __bf16* xs  = dir ? xs1 : xs0;
  __bf16*       res = dir ? res1 : res0;
  const float*  dg  = dir ? dg1 : dg0;
  const float*  ALf = dir ? ALf1 : ALf0;
  const __bf16* Dp  = dir ? Dp1 : Dp0;

  const int b   = blockIdx.y;
  const int c   = blockIdx.x >> 1;
  const int dg_ = blockIdx.x & 1;
  const int tid = threadIdx.x;
  const int d   = dg_*256 + tid;
  const int db  = dir*8 + b;
  const long row0 = (long)b*L_ + c*CT;

  __shared__ float sBC[CT][32];
  if (tid < CT*8){ int e = tid*4; int t = e>>5, cc = e&31;
    *(f32x4*)&sBC[t][cc] = *(const f32x4*)(xd + (row0+t)*48 + 16 + cc); }

  float A[16];
  { const f32x4* p = (const f32x4*)(ALf + d*DS);
    #pragma unroll
    for (int q=0;q<4;q++){ f32x4 v=p[q];
      A[q*4]=-__expf(v[0]); A[q*4+1]=-__expf(v[1]); A[q*4+2]=-__expf(v[2]); A[q*4+3]=-__expf(v[3]); } }
  bool pow_ok = true;
  #pragma unroll
  for (int n=0;n<16;n++) pow_ok = pow_ok && (fabsf(A[n] + (float)(n+1)) < 0.003f*(n+1));

  float h[16];
  { long hb = (((long)db*NC + c)*DI + d)*16;
    const f32x4* p = (const f32x4*)(Hbuf + hb);
    #pragma unroll
    for (int q=0;q<4;q++){ f32x4 v = p[q]; h[q*4]=v[0]; h[q*4+1]=v[1]; h[q*4+2]=v[2]; h[q*4+3]=v[3]; } }
  const float Dpv = (float)Dp[d];
  __syncthreads();

  if (pow_ok){
    #pragma unroll 2
    for (int t=0;t<CT;t++){
      long row = row0 + t;
      f32x4 b0 = *(const f32x4*)&sBC[t][0];
      f32x4 b1 = *(const f32x4*)&sBC[t][4];
      f32x4 b2 = *(const f32x4*)&sBC[t][8];
      f32x4 b3 = *(const f32x4*)&sBC[t][12];
      f32x4 c0 = *(const f32x4*)&sBC[t][16];
      f32x4 c1 = *(const f32x4*)&sBC[t][20];
      f32x4 c2 = *(const f32x4*)&sBC[t][24];
      f32x4 c3 = *(const f32x4*)&sBC[t][28];
      float delta = dg[row*DI + d];
      float xv = (float)xs[row*DI + d];
      float dx = delta*xv;
      float pw[16];
      pow_tree(__expf(-delta), pw);
      float Bv[16] = {b0[0],b0[1],b0[2],b0[3], b1[0],b1[1],b1[2],b1[3],
                      b2[0],b2[1],b2[2],b2[3], b3[0],b3[1],b3[2],b3[3]};
      float Cv[16] = {c0[0],c0[1],c0[2],c0[3], c1[0],c1[1],c1[2],c1[3],
                      c2[0],c2[1],c2[2],c2[3], c3[0],c3[1],c3[2],c3[3]};
      float p = 0.f;
      #pragma unroll
      for (int n=0;n<16;n++){
        h[n] = pw[n]*h[n] + dx*Bv[n];
        p += h[n]*Cv[n];
      }
      float yv = p + Dpv*xv;
      float rv = (float)res[row*DI + d];
      res[row*DI + d] = (__bf16)(yv * silu_f(rv));
    }
  } else {
    #pragma unroll 2
    for (int t=0;t<CT;t++){
      long row = row0 + t;
      f32x4 b0 = *(const f32x4*)&sBC[t][0];
      f32x4 b1 = *(const f32x4*)&sBC[t][4];
      f32x4 b2 = *(const f32x4*)&sBC[t][8];
      f32x4 b3 = *(const f32x4*)&sBC[t][12];
      f32x4 c0 = *(const f32x4*)&sBC[t][16];
      f32x4 c1 = *(const f32x4*)&sBC[t][20];
      f32x4 c2 = *(const f32x4*)&sBC[t][24];
      f32x4 c3 = *(const f32x4*)&sBC[t][28];
      float delta = dg[row*DI + d];
      float xv = (float)xs[row*DI + d];
      float dx = delta*xv;
      float Bv[16] = {b0[0],b0[1],b0[2],b0[3], b1[0],b1[1],b1[2],b1[3],
                      b2[0],b2[1],b2[2],b2[3], b3[0],b3[1],b3[2],b3[3]};
      float Cv[16] = {c0[0],c0[1],c0[2],c0[3], c1[0],c1[1],c1[2],c1[3],
                      c2[0],c2[1],c2[2],c2[3], c3[0],c3[1],c3[2],c3[3]};
      float p = 0.f;
      #pragma unroll
      for (int n=0;n<16;n++){
        h[n] = __expf(delta*A[n])*h[n] + dx*Bv[n];
        p += h[n]*Cv[n];
      }
      float yv = p + Dpv*xv;
      float rv = (float)res[row*DI + d];
      res[row*DI + d] = (__bf16)(yv * silu_f(rv));
    }
  }
}

// ---------------- FALLBACK scan ----------------
__global__ __launch_bounds__(256) void scan_k(
    const float* xd0, const float* xd1,
    const __bf16* xs0, const __bf16* xs1,
    __bf16* res0, __bf16* res1,
    const float* dw0, const float* dw1,
    const __bf16* dtB0, const __bf16* dtB1,
    const __bf16* AL0, const __bf16* AL1,
    const __bf16* Dp0, const __bf16* Dp1)
{
  const int dir = blockIdx.z;
  const float*  xd  = dir ? xd1 : xd0;
  const __bf16* xs  = dir ? xs1 : xs0;
  __bf16*       res = dir ? res1 : res0;
  const float*  dw  = dir ? dw1 : dw0;
  const __bf16* dtB = dir ? dtB1 : dtB0;
  const __bf16* AL  = dir ? AL1 : AL0;
  const __bf16* Dp  = dir ? Dp1 : Dp0;

  const int b  = blockIdx.y;
  const int dt = blockIdx.x;
  const int tid = threadIdx.x;
  const int n  = tid & 15;
  const int dl = tid >> 4;
  const int d  = dt*16 + dl;

  __shared__ float sxd[128][48];
  __shared__ float sx[128][16];
  __shared__ float sdelta[128][16];
  __shared__ float sy[128][16];
  __shared__ float sdw[16][17];
  __shared__ float sdb[16];

  sdw[dl][n] = dw[(dt*16+dl)*DTR + n];
  if (tid < 16) sdb[tid] = (float)dtB[dt*16 + tid];
  const float A_dn = -__expf((float)AL[d*DS + n]);
  float h = 0.f;
  __syncthreads();

  const long rowB = (long)b * L_;
  for (int c0=0; c0<L_; c0+=128){
    #pragma unroll 1
    for (int k=0;k<24;k++){
      int e = tid + k*256;
      int t = e / 48, col = e - t*48;
      sxd[t][col] = xd[(rowB + c0 + t)*48 + col];
    }
    #pragma unroll 1
    for (int k=0;k<8;k++){
      int e = tid + k*256;
      int t = e >> 4, dc = e & 15;
      sx[t][dc] = (float)xs[(rowB + c0 + t)*DI + dt*16 + dc];
    }
    __syncthreads();
    #pragma unroll 1
    for (int k=0;k<8;k++){
      int e = tid + k*256;
      int t = e >> 4, dc = e & 15;
      float z = sdb[dc];
      #pragma unroll
      for (int q=0;q<16;q++) z += sxd[t][q] * sdw[dc][q];
      sdelta[t][dc] = softplus_f(z);
    }
    __syncthreads();
    #pragma unroll 2
    for (int tt=0;tt<128;tt++){
      float delta = sdelta[tt][dl];
      float xv = sx[tt][dl];
      float Bv = sxd[tt][16+n];
      float Cv = sxd[tt][32+n];
      float dA = __expf(delta * A_dn);
      h = dA*h + (delta*xv)*Bv;
      float p = h * Cv;
      p += __shfl_xor(p, 1);
      p += __shfl_xor(p, 2);
      p += __shfl_xor(p, 4);
      p += __shfl_xor(p, 8);
      if (n == 0) sy[tt][dl] = p;
    }
    __syncthreads();
    #pragma unroll 1
    for (int k=0;k<8;k++){
      int e = tid + k*256;
      int t = e >> 4, dc = e & 15;
      long row = rowB + c0 + t;
      float yv = sy[t][dc] + (float)Dp[dt*16+dc] * sx[t][dc];
      float rv = (float)res[row*DI + dt*16 + dc];
      res[row*DI + dt*16 + dc] = (__bf16)(yv * silu_f(rv));
    }
    __syncthreads();
  }
}

// ---------------- launch ----------------
extern "C" void kernel_launch(void* const* d_in, const int* in_sizes, int n_in,
                              void* d_out, int out_size, void* d_ws, size_t ws_size,
                              hipStream_t stream)
{
  const size_t MB = 1u<<20;
  if (ws_size < 61*MB) return;
  const bool newscan = (ws_size >= 160*MB);

  char* w = (char*)d_ws;
  __bf16* xz[2]  = {(__bf16*)(w + 0),      (__bf16*)(w + 8*MB)};
  __bf16* res[2] = {(__bf16*)(w + 16*MB),  (__bf16*)(w + 24*MB)};
  __bf16* xsc[2] = {(__bf16*)(w + 32*MB),  (__bf16*)(w + 40*MB)};
  __bf16* xn     = (__bf16*)(w + 48*MB);
  float*  xdbl[2]= {(float*)(w + 48*MB),   (float*)(w + 48*MB + (size_t)M_*48*4)};
  __bf16* fusedIn = xsc[0];

  char* wp = w + 52*MB;
  auto carve = [&](size_t bytes)->void*{
    void* p = wp;
    wp += (bytes + 255) & ~(size_t)255;
    return p;
  };
  __bf16 *inWt[2], *xWt[2], *outWt[2];
  float *dtWt[2], *convWt[2];
  for (int m=0;m<2;m++){
    inWt[m]   = (__bf16*)carve((size_t)(2*DI)*DM*2);
    xWt[m]    = (__bf16*)carve((size_t)48*DI*2);
    outWt[m]  = (__bf16*)carve((size_t)DM*DI*2);
    dtWt[m]   = (float*)carve((size_t)DI*DTR*4);
    convWt[m] = (float*)carve((size_t)4*DI*4);
  }
  __bf16* fusWt = (__bf16*)carve((size_t)DM*DI*2);
  int* flag = (int*)carve(256);
  float* ALf[2] = {(float*)carve((size_t)DI*DS*4), (float*)carve((size_t)DI*DS*4)};

  char* cp = w + 55*MB;
  auto carve2 = [&](size_t elems)->__bf16*{
    __bf16* p = (__bf16*)cp;
    cp += (elems*2 + 255) & ~(size_t)255;
    return p;
  };
  __bf16* ngc = carve2(DM);
  __bf16* nbc = carve2(DM);
  __bf16 *convBc[2], *dtBc[2], *ALc[2], *Dpc[2];
  for (int m=0;m<2;m++){
    convBc[m] = carve2(DI);
    dtBc[m]   = carve2(DI);
    ALc[m]    = carve2((size_t)DI*DS);
    Dpc[m]    = carve2(DI);
  }
  __bf16* fusBc = carve2(DM);

  float* dgA[2] = {(float*)(w + 56*MB), (float*)(w + 72*MB)};
  float* hend = (float*)(w + 88*MB);
  float* sumd = (float*)(w + 122*MB);
  float* Hbuf = (float*)(w + 125*MB);

  probe_k<<<1, 256, 0, stream>>>(d_in[0], flag);

  CvtArgs ca;
  int ci = 0;
  ca.j[ci++] = {d_in[1],  ngc, DM};
  ca.j[ci++] = {d_in[2],  nbc, DM};
  for (int m=0;m<2;m++){
    int base = 3 + m*9;
    ca.j[ci++] = {d_in[base+2], convBc[m], DI};
    ca.j[ci++] = {d_in[base+5], dtBc[m],   DI};
    ca.j[ci++] = {d_in[base+6], ALc[m],    DI*DS};
    ca.j[ci++] = {d_in[base+7], Dpc[m],    DI};
  }
  ca.j[ci++] = {d_in[22], fusBc, DM};
  cvt_k<<<79, 256, 0, stream>>>(ca, flag);
  cvtA_k<<<64, 256, 0, stream>>>(d_in[9], d_in[18], ALf[0], ALf[1], flag);

  PrepArgs pa;
  int ji = 0;
  for (int m=0;m<2;m++){
    int base = 3 + m*9;
    pa.j[ji++] = {d_in[base+0], inWt[m],  DM,  2*DI, 0};
    pa.j[ji++] = {d_in[base+3], xWt[m],   DI,  48,   0};
    pa.j[ji++] = {d_in[base+8], outWt[m], DI,  DM,   0};
    pa.j[ji++] = {d_in[base+4], dtWt[m],  DTR, DI,   1};
    pa.j[ji++] = {d_in[base+1], convWt[m],DI,  4,    1};
  }
  pa.j[ji++] = {d_in[21], fusWt, DI, DM, 0};
  prep_k<<<(987136+255)/256, 256, 0, stream>>>(pa, flag);

  ln_k<<<M_, 256, 0, stream>>>(d_in[0], ngc, nbc, xn, flag);
  // in-proj: [8192,256] x [256,1024], LDS-staged, split store
  gemm_lds_k<128,128,0,256><<<dim3(M_/128, (2*DI)/128, 2), 256, 0, stream>>>(
      xn, xn, inWt[0], inWt[1], xz[0], xz[1], DM, DM, DI, res[0], res[1], nullptr);
  conv_k<<<dim3((M_*64)/256, 1, 2), 256, 0, stream>>>(
      xz[0], xz[1], convWt[0], convWt[1], convBc[0], convBc[1], xsc[0], xsc[1]);
  // x-proj: [8192,512] x [512,48] -> f32 (register GEMM)
  gemm_r_k<1,3,4,1,512><<<dim3(M_/64, 1, 2), 256, 0, stream>>>(
      xsc[0], xsc[1], xWt[0], xWt[1], xdbl[0], xdbl[1], DI, DI, 48);

  if (newscan){
    dt_k<<<dim3(M_/32, 1, 2), 256, 0, stream>>>(
        xdbl[0], xdbl[1], dtWt[0], dtWt[1], dtBc[0], dtBc[1], dgA[0], dgA[1]);
    scanA_k<<<dim3(NC*2, B_, 2), 256, 0, stream>>>(
        xdbl[0], xdbl[1], xsc[0], xsc[1], dgA[0], dgA[1], ALf[0], ALf[1], hend, sumd);
    scanB_k<<<131072/256, 256, 0, stream>>>(ALf[0], ALf[1], hend, sumd, Hbuf);
    scanC_k<<<dim3(NC*2, B_, 2), 256, 0, stream>>>(
        xdbl[0], xdbl[1], xsc[0], xsc[1], res[0], res[1],
        dgA[0], dgA[1], ALf[0], ALf[1], Dpc[0], Dpc[1], Hbuf);
  } else {
    scan_k<<<dim3(DI/16, B_, 2), 256, 0, stream>>>(
        xdbl[0], xdbl[1], xsc[0], xsc[1], res[0], res[1], dtWt[0], dtWt[1],
        dtBc[0], dtBc[1], ALc[0], ALc[1], Dpc[0], Dpc[1]);
  }

  // out-proj: [8192,512] x [512,256] -> concat (dir1 rows un-flipped on store)
  gemm_lds_k<64,64,2,512><<<dim3(M_/64, DM/64, 2), 256, 0, stream>>>(
      res[0], res[1], outWt[0], outWt[1], fusedIn, fusedIn, DI, DI, 2*DM, nullptr, nullptr, nullptr);
  // fuse: [8192,512] x [512,256] + bias + residual
  gemm_lds_k<64,64,3,512><<<dim3(M_/64, DM/64, 1), 256, 0, stream>>>(
      fusedIn, fusedIn, fusWt, fusWt, d_out, d_out, 2*DM, 2*DM, DM, fusBc, d_in[0], flag);
}

// Round 11
// 283.437 us; speedup vs baseline: 1.1709x; 1.0101x over previous
//
#include <hip/hip_runtime.h>
#include <cmath>

typedef __bf16 bf16x8 __attribute__((ext_vector_type(8)));
typedef float  f32x4  __attribute__((ext_vector_type(4)));
typedef float  f32x2  __attribute__((ext_vector_type(2)));

#define B_  8
#define L_  1024
#define DM  256
#define DI  512
#define DS  16
#define DTR 16
#define M_  (B_*L_)
#define NC  64
#define CT  16

__device__ inline float softplus_f(float z){
  return (z > 20.f) ? z : __logf(1.f + __expf(z));
}
__device__ inline float silu_f(float z){
  return z / (1.f + __expf(-z));
}

__device__ inline void pow_tree(float e1, float* p){
  float e2=e1*e1, e4=e2*e2, e8=e4*e4;
  float e3=e2*e1, e5=e4*e1, e6=e4*e2, e7=e4*e3;
  p[0]=e1;  p[1]=e2;  p[2]=e3;  p[3]=e4;
  p[4]=e5;  p[5]=e6;  p[6]=e7;  p[7]=e8;
  p[8]=e8*e1;  p[9]=e8*e2;  p[10]=e8*e3;  p[11]=e8*e4;
  p[12]=e8*e5; p[13]=e8*e6; p[14]=e8*e7;  p[15]=e8*e8;
}

// ---------------- dtype probe ----------------
__global__ __launch_bounds__(256) void probe_k(const void* x, int* flag){
  __shared__ int sbad[256];
  int tid = threadIdx.x;
  const unsigned short* u = (const unsigned short*)x;
  int bad = 0;
  for (int i = tid; i < 4096; i += 256){
    unsigned short v = u[2*i];
    int e = (v >> 7) & 0xFF;
    if (e >= 160 || e < 96) bad++;
  }
  sbad[tid] = bad;
  __syncthreads();
  if (tid == 0){
    int t = 0;
    for (int i=0;i<256;i++) t += sbad[i];
    *flag = (t > 1024) ? 1 : 0;
  }
}

// ---------------- unified prep: transpose / copy / f32-copy, raw per flag ----------------
// rows==1 degenerates to a dtype-converting copy.
struct PrepJob { const void* src; void* dst; int rows; int cols; int f32out; };
struct PrepArgs { PrepJob j[26]; int nj; };

__global__ __launch_bounds__(256) void prep_k(PrepArgs a, const int* flag){
  int e = blockIdx.x*256 + threadIdx.x;
  const int f = *flag;
  #pragma unroll 1
  for (int jj=0; jj<a.nj; jj++){
    int sz = a.j[jj].rows * a.j[jj].cols;
    if (e < sz){
      int cols = a.j[jj].cols;
      int r = e / cols, c = e - r*cols;
      float v = f ? ((const float*)a.j[jj].src)[e] : (float)((const __bf16*)a.j[jj].src)[e];
      if (a.j[jj].f32out) ((float*)a.j[jj].dst)[c*a.j[jj].rows + r] = v;
      else ((__bf16*)a.j[jj].dst)[(long)c*a.j[jj].rows + r] = (__bf16)v;
      return;
    }
    e -= sz;
  }
}

// ---------------- LayerNorm ----------------
__global__ __launch_bounds__(256) void ln_k(const void* x, const __bf16* g,
                                            const __bf16* bb, __bf16* xn, const int* flag){
  const int row = blockIdx.x;
  const int d = threadIdx.x;
  const int f = *flag;
  long idx = (long)row*DM + d;
  float v = f ? ((const float*)x)[idx] : (float)(((const __bf16*)x)[idx]);
  float s = v, q = v*v;
  #pragma unroll
  for (int off=32; off>0; off>>=1){
    s += __shfl_down(s, off);
    q += __shfl_down(q, off);
  }
  __shared__ float ss[4], sq[4];
  int w = d >> 6, ln = d & 63;
  if (ln == 0){ ss[w] = s; sq[w] = q; }
  __syncthreads();
  s = ss[0]+ss[1]+ss[2]+ss[3];
  q = sq[0]+sq[1]+sq[2]+sq[3];
  float mu  = s * (1.f/DM);
  float var = q * (1.f/DM) - mu*mu;
  float xnv = (v - mu) * rsqrtf(var + 1e-5f) * (float)g[d] + (float)bb[d];
  xn[idx] = (__bf16)xnv;
}

// ============ LDS-staged MFMA GEMM (in-proj): C=A*Bt^T, split store ============
template<int BM,int BN,int KK>
__global__ __launch_bounds__(256) void gemm_in_k(
    const __bf16* A, const __bf16* B0, const __bf16* B1,
    __bf16* xz0, __bf16* xz1, __bf16* res0, __bf16* res1,
    int lda, int ldb)
{
  constexpr int TM = BM/2, TN = BN/2;
  constexpr int WMT = TM/16, WNT = TN/16;
  constexpr int LA = BM/64, LB = BN/64;

  const int dir = blockIdx.z;
  const __bf16* Bt = dir ? B1 : B0;
  __bf16* xz  = dir ? xz1 : xz0;
  __bf16* res = dir ? res1 : res0;
  const int tid  = threadIdx.x;
  const int lane = tid & 63;
  const int wid  = tid >> 6;
  const int wm = wid & 1;
  const int wn = wid >> 1;
  const int mBase = blockIdx.x * BM;
  const int nBase = blockIdx.y * BN;
  const int lm = lane & 15;
  const int kq = (lane >> 4) * 8;

  __shared__ __bf16 As[BM*32];
  __shared__ __bf16 Bs[BN*32];

  const __bf16* aS[LA];
  const __bf16* bS[LB];
  {
    int colk = (tid & 3) * 8;
    #pragma unroll
    for (int ld=0; ld<LA; ld++){
      int r = mBase + ld*64 + (tid >> 2);
      if (dir==1){ int b = r >> 10, t = r & (L_-1); r = (b<<10) + (L_-1-t); }
      aS[ld] = A + (long)r*lda + colk;
    }
    #pragma unroll
    for (int ld=0; ld<LB; ld++){
      int r = nBase + ld*64 + (tid >> 2);
      bS[ld] = Bt + (long)r*ldb + colk;
    }
  }

  f32x4 acc[WMT][WNT] = {};
  for (int k0=0; k0<KK; k0+=32){
    #pragma unroll
    for (int ld=0; ld<LA; ld++)
      __builtin_amdgcn_global_load_lds(
        (const __attribute__((address_space(1))) void*)(aS[ld] + k0),
        (__attribute__((address_space(3))) void*)(&As[ld*2048 + tid*8]), 16, 0, 0);
    #pragma unroll
    for (int ld=0; ld<LB; ld++)
      __builtin_amdgcn_global_load_lds(
        (const __attribute__((address_space(1))) void*)(bS[ld] + k0),
        (__attribute__((address_space(3))) void*)(&Bs[ld*2048 + tid*8]), 16, 0, 0);
    __syncthreads();
    bf16x8 af[WMT], bfr[WNT];
    #pragma unroll
    for (int i=0;i<WMT;i++) af[i]  = *(const bf16x8*)&As[(wm*TM + i*16 + lm)*32 + kq];
    #pragma unroll
    for (int j=0;j<WNT;j++) bfr[j] = *(const bf16x8*)&Bs[(wn*TN + j*16 + lm)*32 + kq];
    #pragma unroll
    for (int i=0;i<WMT;i++)
      #pragma unroll
      for (int j=0;j<WNT;j++)
        acc[i][j] = __builtin_amdgcn_mfma_f32_16x16x32_bf16(af[i], bfr[j], acc[i][j], 0,0,0);
    __syncthreads();
  }

  #pragma unroll
  for (int i=0;i<WMT;i++){
    #pragma unroll
    for (int rr=0;rr<4;rr++){
      int r = mBase + wm*TM + i*16 + (lane>>4)*4 + rr;
      #pragma unroll
      for (int j=0;j<WNT;j++){
        int c = nBase + wn*TN + j*16 + lm;
        float v = acc[i][j][rr];
        if (c < DI) xz[(long)r*DI + c] = (__bf16)v;
        else        res[(long)r*DI + (c-DI)] = (__bf16)v;
      }
    }
  }
}

// ============ final fused GEMM: out = yg_f@Wc0 + flip(yg_b)@Wc1 + fusB + x ============
template<int BM,int BN,int KK>
__global__ __launch_bounds__(256) void gemm_fin_k(
    const __bf16* Af, const __bf16* Ab,       // res[0], res[1] (yg), lda=DI
    const __bf16* Bt0, const __bf16* Bt1,     // BtC[c][k], ldb=DI
    void* Cout, const __bf16* bias, const void* resid, const int* outflag)
{
  constexpr int TM = BM/2, TN = BN/2;
  constexpr int WMT = TM/16, WNT = TN/16;
  constexpr int LA = BM/64, LB = BN/64;

  const int tid  = threadIdx.x;
  const int lane = tid & 63;
  const int wid  = tid >> 6;
  const int wm = wid & 1;
  const int wn = wid >> 1;
  const int mBase = blockIdx.x * BM;
  const int nBase = blockIdx.y * BN;
  const int lm = lane & 15;
  const int kq = (lane >> 4) * 8;
  const int of = outflag ? *outflag : 0;

  __shared__ __bf16 As[BM*32];
  __shared__ __bf16 Bs[BN*32];

  f32x4 acc[WMT][WNT] = {};
  #pragma unroll 1
  for (int dd=0; dd<2; dd++){
    const __bf16* A  = dd ? Ab  : Af;
    const __bf16* Bt = dd ? Bt1 : Bt0;
    const __bf16* aS[LA];
    const __bf16* bS[LB];
    {
      int colk = (tid & 3) * 8;
      #pragma unroll
      for (int ld=0; ld<LA; ld++){
        int r = mBase + ld*64 + (tid >> 2);
        if (dd==1){ int b = r >> 10, t = r & (L_-1); r = (b<<10) + (L_-1-t); }
        aS[ld] = A + (long)r*DI + colk;
      }
      #pragma unroll
      for (int ld=0; ld<LB; ld++){
        int r = nBase + ld*64 + (tid >> 2);
        bS[ld] = Bt + (long)r*DI + colk;
      }
    }
    for (int k0=0; k0<KK; k0+=32){
      #pragma unroll
      for (int ld=0; ld<LA; ld++)
        __builtin_amdgcn_global_load_lds(
          (const __attribute__((address_space(1))) void*)(aS[ld] + k0),
          (__attribute__((address_space(3))) void*)(&As[ld*2048 + tid*8]), 16, 0, 0);
      #pragma unroll
      for (int ld=0; ld<LB; ld++)
        __builtin_amdgcn_global_load_lds(
          (const __attribute__((address_space(1))) void*)(bS[ld] + k0),
          (__attribute__((address_space(3))) void*)(&Bs[ld*2048 + tid*8]), 16, 0, 0);
      __syncthreads();
      bf16x8 af[WMT], bfr[WNT];
      #pragma unroll
      for (int i=0;i<WMT;i++) af[i]  = *(const bf16x8*)&As[(wm*TM + i*16 + lm)*32 + kq];
      #pragma unroll
      for (int j=0;j<WNT;j++) bfr[j] = *(const bf16x8*)&Bs[(wn*TN + j*16 + lm)*32 + kq];
      #pragma unroll
      for (int i=0;i<WMT;i++)
        #pragma unroll
        for (int j=0;j<WNT;j++)
          acc[i][j] = __builtin_amdgcn_mfma_f32_16x16x32_bf16(af[i], bfr[j], acc[i][j], 0,0,0);
      __syncthreads();
    }
  }

  #pragma unroll
  for (int i=0;i<WMT;i++){
    #pragma unroll
    for (int rr=0;rr<4;rr++){
      int r = mBase + wm*TM + i*16 + (lane>>4)*4 + rr;
      #pragma unroll
      for (int j=0;j<WNT;j++){
        int c = nBase + wn*TN + j*16 + lm;
        float v = acc[i][j][rr];
        float rsd = of ? ((const float*)resid)[(long)r*DM + c]
                       : (float)((const __bf16*)resid)[(long)r*DM + c];
        v += (float)bias[c] + rsd;
        if (of) ((float*)Cout)[(long)r*DM + c] = v;
        else    ((__bf16*)Cout)[(long)r*DM + c] = (__bf16)v;
      }
    }
  }
}

// ---------------- register GEMM: x-proj (f32 out) / wcomb (bf16 out) ----------------
template<int WMT,int WNT,int BWM,int BWN,int KK,int BF16OUT>
__global__ __launch_bounds__(64*BWM*BWN) void gemm_r_k(
    const __bf16* A0, const __bf16* A1,
    const __bf16* B0, const __bf16* B1,
    void* C0, void* C1,
    int lda, int ldb, int ldc)
{
  const int dir = blockIdx.z;
  const __bf16* A  = dir ? A1 : A0;
  const __bf16* Bt = dir ? B1 : B0;
  void* C = dir ? C1 : C0;
  const int tid  = threadIdx.x;
  const int lane = tid & 63;
  const int wid  = tid >> 6;
  const int wm = wid % BWM;
  const int wn = wid / BWM;
  const int mBase = (blockIdx.x*BWM + wm) * (WMT*16);
  const int nBase = (blockIdx.y*BWN + wn) * (WNT*16);
  const int lm = lane & 15;
  const int kq = (lane >> 4) * 8;

  long aoff[WMT];
  #pragma unroll
  for (int i=0;i<WMT;i++) aoff[i] = (long)(mBase + i*16 + lm) * lda + kq;
  long boff[WNT];
  #pragma unroll
  for (int j=0;j<WNT;j++) boff[j] = (long)(nBase + j*16 + lm) * ldb + kq;

  f32x4 acc[WMT][WNT] = {};
  #pragma unroll
  for (int k0=0; k0<KK; k0+=32){
    bf16x8 af[WMT], bfr[WNT];
    #pragma unroll
    for (int i=0;i<WMT;i++) af[i]  = *(const bf16x8*)(A  + aoff[i] + k0);
    #pragma unroll
    for (int j=0;j<WNT;j++) bfr[j] = *(const bf16x8*)(Bt + boff[j] + k0);
    #pragma unroll
    for (int i=0;i<WMT;i++)
      #pragma unroll
      for (int j=0;j<WNT;j++)
        acc[i][j] = __builtin_amdgcn_mfma_f32_16x16x32_bf16(af[i], bfr[j], acc[i][j], 0,0,0);
  }

  #pragma unroll
  for (int i=0;i<WMT;i++)
    #pragma unroll
    for (int rr=0;rr<4;rr++){
      int r = mBase + i*16 + (lane>>4)*4 + rr;
      #pragma unroll
      for (int j=0;j<WNT;j++){
        int c = nBase + j*16 + lm;
        if (BF16OUT) ((__bf16*)C)[(long)r*ldc + c] = (__bf16)acc[i][j][rr];
        else         ((float*)C)[(long)r*ldc + c] = acc[i][j][rr];
      }
    }
}

// ---------------- causal depthwise conv (DC=4) + SiLU ----------------
__global__ __launch_bounds__(256) void conv_k(
    const __bf16* xz0, const __bf16* xz1,
    const float* cw0, const float* cw1,
    const __bf16* cb0, const __bf16* cb1,
    __bf16* xs0, __bf16* xs1)
{
  const int dir = blockIdx.z;
  const __bf16* xz = dir ? xz1 : xz0;
  const float*  cw = dir ? cw1 : cw0;
  const __bf16* cb = dir ? cb1 : cb0;
  __bf16* xs = dir ? xs1 : xs0;

  int gid = blockIdx.x*256 + threadIdx.x;
  int c8 = gid & 63;
  int t  = (gid >> 6) & (L_-1);
  int b  = gid >> 16;
  int cbase = c8*8;

  float acc[8];
  bf16x8 bb = *(const bf16x8*)(cb + cbase);
  #pragma unroll
  for (int c=0;c<8;c++) acc[c] = (float)bb[c];
  #pragma unroll
  for (int j=0;j<4;j++){
    int tj = t - 3 + j;
    if (tj >= 0){
      bf16x8 xv = *(const bf16x8*)(xz + ((long)(b*L_ + tj))*DI + cbase);
      #pragma unroll
      for (int c=0;c<8;c++) acc[c] += (float)xv[c] * cw[j*DI + cbase + c];
    }
  }
  bf16x8 outv;
  #pragma unroll
  for (int c=0;c<8;c++) outv[c] = (__bf16)silu_f(acc[c]);
  *(bf16x8*)(xs + ((long)(b*L_ + t))*DI + cbase) = outv;
}

// ============ dt-proj ============
__global__ __launch_bounds__(256) void dt_k(
    const float* xd0, const float* xd1,
    const float* dw0, const float* dw1,
    const __bf16* dtB0, const __bf16* dtB1,
    float* dg0, float* dg1)
{
  const int dir = blockIdx.z;
  const float*  xd  = dir ? xd1 : xd0;
  const float*  dw  = dir ? dw1 : dw0;
  const __bf16* dtB = dir ? dtB1 : dtB0;
  float* dg = dir ? dg1 : dg0;
  const long row0 = (long)blockIdx.x * 32;
  const int tid = threadIdx.x;

  __shared__ float sdlt[32][16];
  { int e = tid*2; int r = e>>4, q = e&15;
    *(f32x2*)&sdlt[r][q] = *(const f32x2*)(xd + (row0+r)*48 + q); }

  const int d0 = tid, d1 = tid + 256;
  float dwa[16], dwb[16];
  { const f32x4* p = (const f32x4*)(dw + d0*DTR);
    #pragma unroll
    for (int q=0;q<4;q++){ f32x4 v=p[q]; dwa[q*4]=v[0]; dwa[q*4+1]=v[1]; dwa[q*4+2]=v[2]; dwa[q*4+3]=v[3]; } }
  { const f32x4* p = (const f32x4*)(dw + d1*DTR);
    #pragma unroll
    for (int q=0;q<4;q++){ f32x4 v=p[q]; dwb[q*4]=v[0]; dwb[q*4+1]=v[1]; dwb[q*4+2]=v[2]; dwb[q*4+3]=v[3]; } }
  const float b0v = (float)dtB[d0];
  const float b1v = (float)dtB[d1];
  __syncthreads();

  #pragma unroll 4
  for (int r=0;r<32;r++){
    f32x4 q0 = *(const f32x4*)&sdlt[r][0];
    f32x4 q1 = *(const f32x4*)&sdlt[r][4];
    f32x4 q2 = *(const f32x4*)&sdlt[r][8];
    f32x4 q3 = *(const f32x4*)&sdlt[r][12];
    float z0 = b0v, z1 = b1v;
    z0 += q0[0]*dwa[0]+q0[1]*dwa[1]+q0[2]*dwa[2]+q0[3]*dwa[3];
    z0 += q1[0]*dwa[4]+q1[1]*dwa[5]+q1[2]*dwa[6]+q1[3]*dwa[7];
    z0 += q2[0]*dwa[8]+q2[1]*dwa[9]+q2[2]*dwa[10]+q2[3]*dwa[11];
    z0 += q3[0]*dwa[12]+q3[1]*dwa[13]+q3[2]*dwa[14]+q3[3]*dwa[15];
    z1 += q0[0]*dwb[0]+q0[1]*dwb[1]+q0[2]*dwb[2]+q0[3]*dwb[3];
    z1 += q1[0]*dwb[4]+q1[1]*dwb[5]+q1[2]*dwb[6]+q1[3]*dwb[7];
    z1 += q2[0]*dwb[8]+q2[1]*dwb[9]+q2[2]*dwb[10]+q2[3]*dwb[11];
    z1 += q3[0]*dwb[12]+q3[1]*dwb[13]+q3[2]*dwb[14]+q3[3]*dwb[15];
    dg[(row0+r)*DI + d0] = softplus_f(z0);
    dg[(row0+r)*DI + d1] = softplus_f(z1);
  }
}

// ============ scan phase A ============
__global__ __launch_bounds__(256) void scanA_k(
    const float* xd0, const float* xd1,
    const __bf16* xs0, const __bf16* xs1,
    const float* dg0, const float* dg1,
    const float* ALf0, const float* ALf1,
    float* hend, float* sumd)
{
  const int dir = blockIdx.z;
  const float*  xd  = dir ? xd1 : xd0;
  const __bf16* xs  = dir ? xs1 : xs0;
  const float*  dg  = dir ? dg1 : dg0;
  const float*  ALf = dir ? ALf1 : ALf0;

  const int b   = blockIdx.y;
  const int c   = blockIdx.x >> 1;
  const int dg_ = blockIdx.x & 1;
  const int tid = threadIdx.x;
  const int d   = dg_*256 + tid;
  const int db  = dir*8 + b;
  const long row0 = (long)b*L_ + c*CT;

  __shared__ float sB[CT][16];
  if (tid < CT*4){ int e = tid*4; int t = e>>4, n = e&15;
    *(f32x4*)&sB[t][n] = *(const f32x4*)(xd + (row0+t)*48 + 16 + n); }

  float A[16];
  { const f32x4* p = (const f32x4*)(ALf + d*DS);
    #pragma unroll
    for (int q=0;q<4;q++){ f32x4 v=p[q];
      A[q*4]=-__expf(v[0]); A[q*4+1]=-__expf(v[1]); A[q*4+2]=-__expf(v[2]); A[q*4+3]=-__expf(v[3]); } }
  bool pow_ok = true;
  #pragma unroll
  for (int n=0;n<16;n++) pow_ok = pow_ok && (fabsf(A[n] + (float)(n+1)) < 0.003f*(n+1));

  float h[16];
  #pragma unroll
  for (int n=0;n<16;n++) h[n]=0.f;
  float sdelta = 0.f;
  __syncthreads();

  if (pow_ok){
    #pragma unroll 2
    for (int t=0;t<CT;t++){
      long row = row0 + t;
      f32x4 b0 = *(const f32x4*)&sB[t][0];
      f32x4 b1 = *(const f32x4*)&sB[t][4];
      f32x4 b2 = *(const f32x4*)&sB[t][8];
      f32x4 b3 = *(const f32x4*)&sB[t][12];
      float delta = dg[row*DI + d];
      sdelta += delta;
      float xv = (float)xs[row*DI + d];
      float dx = delta*xv;
      float pw[16];
      pow_tree(__expf(-delta), pw);
      float Bv[16] = {b0[0],b0[1],b0[2],b0[3], b1[0],b1[1],b1[2],b1[3],
                      b2[0],b2[1],b2[2],b2[3], b3[0],b3[1],b3[2],b3[3]};
      #pragma unroll
      for (int n=0;n<16;n++)
        h[n] = pw[n]*h[n] + dx*Bv[n];
    }
  } else {
    #pragma unroll 2
    for (int t=0;t<CT;t++){
      long row = row0 + t;
      f32x4 b0 = *(const f32x4*)&sB[t][0];
      f32x4 b1 = *(const f32x4*)&sB[t][4];
      f32x4 b2 = *(const f32x4*)&sB[t][8];
      f32x4 b3 = *(const f32x4*)&sB[t][12];
      float delta = dg[row*DI + d];
      sdelta += delta;
      float xv = (float)xs[row*DI + d];
      float dx = delta*xv;
      float Bv[16] = {b0[0],b0[1],b0[2],b0[3], b1[0],b1[1],b1[2],b1[3],
                      b2[0],b2[1],b2[2],b2[3], b3[0],b3[1],b3[2],b3[3]};
      #pragma unroll
      for (int n=0;n<16;n++)
        h[n] = __expf(delta*A[n])*h[n] + dx*Bv[n];
    }
  }

  long hb = (((long)db*NC + c)*DI + d)*16;
  f32x4* hp = (f32x4*)(hend + hb);
  #pragma unroll
  for (int q=0;q<4;q++){ f32x4 v; v[0]=h[q*4]; v[1]=h[q*4+1]; v[2]=h[q*4+2]; v[3]=h[q*4+3]; hp[q]=v; }
  sumd[((long)db*NC + c)*DI + d] = sdelta;
}

// ============ phase B ============
__global__ __launch_bounds__(256) void scanB_k(
    const float* ALf0, const float* ALf1,
    const float* hend, const float* sumd, float* Hbuf)
{
  int gid = blockIdx.x*256 + threadIdx.x;
  int n  = gid & 15;
  int d  = (gid>>4) & 511;
  int db = gid >> 13;
  const float* ALf = (db>=8) ? ALf1 : ALf0;
  float A_dn = -__expf(ALf[d*DS + n]);
  float H = 0.f;
  #pragma unroll 1
  for (int c=0;c<NC;c++){
    long base = (((long)db*NC + c)*DI + d)*16 + n;
    Hbuf[base] = H;
    float S = sumd[((long)db*NC + c)*DI + d];
    H = hend[base] + __expf(A_dn*S)*H;
  }
}

// ============ phase C ============
__global__ __launch_bounds__(256) void scanC_k(
    const float* xd0, const float* xd1,
    const __bf16* xs0, const __bf16* xs1,
    __bf16* res0, __bf16* res1,
    const float* dg0, const float* dg1,
    const float* ALf0, const float* ALf1,
    const __bf16* Dp0, const __bf16* Dp1,
    const float* Hbuf)
{
  const int dir = blockIdx.z;
  const float*  xd  = dir ? xd1 : xd0;
  const __bf16* xs  = dir ? xs1 : xs0;
  __bf16*       res = dir ? res1 : res0;
  const float*  dg  = dir ? dg1 : dg0;
  const float*  ALf = dir ? ALf1 : ALf0;
  const __bf16* Dp  = dir ? Dp1 : Dp0;

  const int b   = blockIdx.y;
  const int c   = blockIdx.x >> 1;
  const int dg_ = blockIdx.x & 1;
  const int tid = threadIdx.x;
  const int d   = dg_*256 + tid;
  const int db  = dir*8 + b;
  const long row0 = (long)b*L_ + c*CT;

  __shared__ float sBC[CT][32];
  if (tid < CT*8){ int e = tid*4; int t = e>>5, cc = e&31;
    *(f32x4*)&sBC[t][cc] = *(const f32x4*)(xd + (row0+t)*48 + 16 + cc); }

  float A[16];
  { const f32x4* p = (const f32x4*)(ALf + d*DS);
    #pragma unroll
    for (int q=0;q<4;q++){ f32x4 v=p[q];
      A[q*4]=-__expf(v[0]); A[q*4+1]=-__expf(v[1]); A[q*4+2]=-__expf(v[2]); A[q*4+3]=-__expf(v[3]); } }
  bool pow_ok = true;
  #pragma unroll
  for (int n=0;n<16;n++) pow_ok = pow_ok && (fabsf(A[n] + (float)(n+1)) < 0.003f*(n+1));

  float h[16];
  { long hb = (((long)db*NC + c)*DI + d)*16;
    const f32x4* p = (const f32x4*)(Hbuf + hb);
    #pragma unroll
    for (int q=0;q<4;q++){ f32x4 v = p[q]; h[q*4]=v[0]; h[q*4+1]=v[1]; h[q*4+2]=v[2]; h[q*4+3]=v[3]; } }
  const float Dpv = (float)Dp[d];
  __syncthreads();

  if (pow_ok){
    #pragma unroll 2
    for (int t=0;t<CT;t++){
      long row = row0 + t;
      f32x4 b0 = *(const f32x4*)&sBC[t][0];
      f32x4 b1 = *(const f32x4*)&sBC[t][4];
      f32x4 b2 = *(const f32x4*)&sBC[t][8];
      f32x4 b3 = *(const f32x4*)&sBC[t][12];
      f32x4 c0 = *(const f32x4*)&sBC[t][16];
      f32x4 c1 = *(const f32x4*)&sBC[t][20];
      f32x4 c2 = *(const f32x4*)&sBC[t][24];
      f32x4 c3 = *(const f32x4*)&sBC[t][28];
      float delta = dg[row*DI + d];
      float xv = (float)xs[row*DI + d];
      float dx = delta*xv;
      float pw[16];
      pow_tree(__expf(-delta), pw);
      float Bv[16] = {b0[0],b0[1],b0[2],b0[3], b1[0],b1[1],b1[2],b1[3],
                      b2[0],b2[1],b2[2],b2[3], b3[0],b3[1],b3[2],b3[3]};
      float Cv[16] = {c0[0],c0[1],c0[2],c0[3], c1[0],c1[1],c1[2],c1[3],
                      c2[0],c2[1],c2[2],c2[3], c3[0],c3[1],c3[2],c3[3]};
      float p = 0.f;
      #pragma unroll
      for (int n=0;n<16;n++){
        h[n] = pw[n]*h[n] + dx*Bv[n];
        p += h[n]*Cv[n];
      }
      float yv = p + Dpv*xv;
      float rv = (float)res[row*DI + d];
      res[row*DI + d] = (__bf16)(yv * silu_f(rv));
    }
  } else {
    #pragma unroll 2
    for (int t=0;t<CT;t++){
      long row = row0 + t;
      f32x4 b0 = *(const f32x4*)&sBC[t][0];
      f32x4 b1 = *(const f32x4*)&sBC[t][4];
      f32x4 b2 = *(const f32x4*)&sBC[t][8];
      f32x4 b3 = *(const f32x4*)&sBC[t][12];
      f32x4 c0 = *(const f32x4*)&sBC[t][16];
      f32x4 c1 = *(const f32x4*)&sBC[t][20];
      f32x4 c2 = *(const f32x4*)&sBC[t][24];
      f32x4 c3 = *(const f32x4*)&sBC[t][28];
      float delta = dg[row*DI + d];
      float xv = (float)xs[row*DI + d];
      float dx = delta*xv;
      float Bv[16] = {b0[0],b0[1],b0[2],b0[3], b1[0],b1[1],b1[2],b1[3],
                      b2[0],b2[1],b2[2],b2[3], b3[0],b3[1],b3[2],b3[3]};
      float Cv[16] = {c0[0],c0[1],c0[2],c0[3], c1[0],c1[1],c1[2],c1[3],
                      c2[0],c2[1],c2[2],c2[3], c3[0],c3[1],c3[2],c3[3]};
      float p = 0.f;
      #pragma unroll
      for (int n=0;n<16;n++){
        h[n] = __expf(delta*A[n])*h[n] + dx*Bv[n];
        p += h[n]*Cv[n];
      }
      float yv = p + Dpv*xv;
      float rv = (float)res[row*DI + d];
      res[row*DI + d] = (__bf16)(yv * silu_f(rv));
    }
  }
}

// ---------------- FALLBACK scan ----------------
__global__ __launch_bounds__(256) void scan_k(
    const float* xd0, const float* xd1,
    const __bf16* xs0, const __bf16* xs1,
    __bf16* res0, __bf16* res1,
    const float* dw0, const float* dw1,
    const __bf16* dtB0, const __bf16* dtB1,
    const __bf16* AL0, const __bf16* AL1,
    const __bf16* Dp0, const __bf16* Dp1)
{
  const int dir = blockIdx.z;
  const float*  xd  = dir ? xd1 : xd0;
  const __bf16* xs  = dir ? xs1 : xs0;
  __bf16*       res = dir ? res1 : res0;
  const float*  dw  = dir ? dw1 : dw0;
  const __bf16* dtB = dir ? dtB1 : dtB0;
  const __bf16* AL  = dir ? AL1 : AL0;
  const __bf16* Dp  = dir ? Dp1 : Dp0;

  const int b  = blockIdx.y;
  const int dt = blockIdx.x;
  const int tid = threadIdx.x;
  const int n  = tid & 15;
  const int dl = tid >> 4;
  const int d  = dt*16 + dl;

  __shared__ float sxd[128][48];
  __shared__ float sx[128][16];
  __shared__ float sdelta[128][16];
  __shared__ float sy[128][16];
  __shared__ float sdw[16][17];
  __shared__ float sdb[16];

  sdw[dl][n] = dw[(dt*16+dl)*DTR + n];
  if (tid < 16) sdb[tid] = (float)dtB[dt*16 + tid];
  const float A_dn = -__expf((float)AL[d*DS + n]);
  float h = 0.f;
  __syncthreads();

  const long rowB = (long)b * L_;
  for (int c0=0; c0<L_; c0+=128){
    #pragma unroll 1
    for (int k=0;k<24;k++){
      int e = tid + k*256;
      int t = e / 48, col = e - t*48;
      sxd[t][col] = xd[(rowB + c0 + t)*48 + col];
    }
    #pragma unroll 1
    for (int k=0;k<8;k++){
      int e = tid + k*256;
      int t = e >> 4, dc = e & 15;
      sx[t][dc] = (float)xs[(rowB + c0 + t)*DI + dt*16 + dc];
    }
    __syncthreads();
    #pragma unroll 1
    for (int k=0;k<8;k++){
      int e = tid + k*256;
      int t = e >> 4, dc = e & 15;
      float z = sdb[dc];
      #pragma unroll
      for (int q=0;q<16;q++) z += sxd[t][q] * sdw[dc][q];
      sdelta[t][dc] = softplus_f(z);
    }
    __syncthreads();
    #pragma unroll 2
    for (int tt=0;tt<128;tt++){
      float delta = sdelta[tt][dl];
      float xv = sx[tt][dl];
      float Bv = sxd[tt][16+n];
      float Cv = sxd[tt][32+n];
      float dA = __expf(delta * A_dn);
      h = dA*h + (delta*xv)*Bv;
      float p = h * Cv;
      p += __shfl_xor(p, 1);
      p += __shfl_xor(p, 2);
      p += __shfl_xor(p, 4);
      p += __shfl_xor(p, 8);
      if (n == 0) sy[tt][dl] = p;
    }
    __syncthreads();
    #pragma unroll 1
    for (int k=0;k<8;k++){
      int e = tid + k*256;
      int t = e >> 4, dc = e & 15;
      long row = rowB + c0 + t;
      float yv = sy[t][dc] + (float)Dp[dt*16+dc] * sx[t][dc];
      float rv = (float)res[row*DI + dt*16 + dc];
      res[row*DI + dt*16 + dc] = (__bf16)(yv * silu_f(rv));
    }
    __syncthreads();
  }
}

// ---------------- launch ----------------
extern "C" void kernel_launch(void* const* d_in, const int* in_sizes, int n_in,
                              void* d_out, int out_size, void* d_ws, size_t ws_size,
                              hipStream_t stream)
{
  const size_t MB = 1u<<20;
  if (ws_size < 61*MB) return;
  const bool newscan = (ws_size >= 160*MB);

  char* w = (char*)d_ws;
  __bf16* xz[2]  = {(__bf16*)(w + 0),      (__bf16*)(w + 8*MB)};
  __bf16* res[2] = {(__bf16*)(w + 16*MB),  (__bf16*)(w + 24*MB)};
  __bf16* xsc[2] = {(__bf16*)(w + 32*MB),  (__bf16*)(w + 40*MB)};
  __bf16* xn     = (__bf16*)(w + 48*MB);
  float*  xdbl[2]= {(float*)(w + 48*MB),   (float*)(w + 48*MB + (size_t)M_*48*4)};

  char* wp = w + 52*MB;
  auto carve = [&](size_t bytes)->void*{
    void* p = wp;
    wp += (bytes + 255) & ~(size_t)255;
    return p;
  };
  __bf16 *inWt[2], *xWt[2], *outWr[2], *BtC[2];
  float *dtWt[2], *convWt[2];
  for (int m=0;m<2;m++){
    inWt[m]   = (__bf16*)carve((size_t)(2*DI)*DM*2);
    xWt[m]    = (__bf16*)carve((size_t)48*DI*2);
    outWr[m]  = (__bf16*)carve((size_t)DI*DM*2);
    BtC[m]    = (__bf16*)carve((size_t)DM*DI*2);
    dtWt[m]   = (float*)carve((size_t)DI*DTR*4);
    convWt[m] = (float*)carve((size_t)4*DI*4);
  }
  __bf16* fusWt = (__bf16*)carve((size_t)DM*(2*DM)*2);
  int* flag = (int*)carve(256);
  float* ALf[2] = {(float*)carve((size_t)DI*DS*4), (float*)carve((size_t)DI*DS*4)};

  char* cp = w + 57*MB;
  auto carve2 = [&](size_t elems)->__bf16*{
    __bf16* p = (__bf16*)cp;
    cp += (elems*2 + 255) & ~(size_t)255;
    return p;
  };
  __bf16* ngc = carve2(DM);
  __bf16* nbc = carve2(DM);
  __bf16 *convBc[2], *dtBc[2], *ALc[2], *Dpc[2];
  for (int m=0;m<2;m++){
    convBc[m] = carve2(DI);
    dtBc[m]   = carve2(DI);
    ALc[m]    = carve2((size_t)DI*DS);
    Dpc[m]    = carve2(DI);
  }
  __bf16* fusBc = carve2(DM);

  float* dgA[2] = {(float*)(w + 58*MB), (float*)(w + 74*MB)};
  float* hend = (float*)(w + 90*MB);
  float* sumd = (float*)(w + 124*MB);
  float* Hbuf = (float*)(w + 127*MB);

  probe_k<<<1, 256, 0, stream>>>(d_in[0], flag);

  // unified prep: 11 transposes + 11 small copies + 2 ALf f32 copies
  PrepArgs pa;
  int ji = 0;
  size_t tot = 0;
  auto addj = [&](const void* s, void* dst, int rows, int cols, int f32o){
    pa.j[ji++] = {s, dst, rows, cols, f32o};
    tot += (size_t)rows*cols;
  };
  for (int m=0;m<2;m++){
    int base = 3 + m*9;
    addj(d_in[base+0], inWt[m],  DM,  2*DI, 0);
    addj(d_in[base+3], xWt[m],   DI,  48,   0);
    addj(d_in[base+8], outWr[m], 1,   DI*DM,0);   // raw bf16 copy
    addj(d_in[base+4], dtWt[m],  DTR, DI,   1);
    addj(d_in[base+1], convWt[m],DI,  4,    1);
    addj(d_in[base+2], convBc[m],1, DI, 0);
    addj(d_in[base+5], dtBc[m],  1, DI, 0);
    addj(d_in[base+6], ALc[m],   1, DI*DS, 0);
    addj(d_in[base+6], (void*)ALf[m], 1, DI*DS, 1);
    addj(d_in[base+7], Dpc[m],   1, DI, 0);
  }
  addj(d_in[21], fusWt, 2*DM, DM, 0);
  addj(d_in[1],  ngc, 1, DM, 0);
  addj(d_in[2],  nbc, 1, DM, 0);
  addj(d_in[22], fusBc, 1, DM, 0);
  pa.nj = ji;
  prep_k<<<(int)((tot+255)/256), 256, 0, stream>>>(pa, flag);

  // wcomb: BtC[m][c][k] = sum_j fusWt[c][m*256+j] * outWr[m][k][j]
  gemm_r_k<1,4,4,1,DM,1><<<dim3(4, 8, 2), 256, 0, stream>>>(
      fusWt, fusWt + DM,                  // A offset m*256 in K (lda=512)
      outWr[0], outWr[1], BtC[0], BtC[1], 2*DM, DM, DI);

  ln_k<<<M_, 256, 0, stream>>>(d_in[0], ngc, nbc, xn, flag);
  gemm_in_k<128,128,256><<<dim3(M_/128, (2*DI)/128, 2), 256, 0, stream>>>(
      xn, inWt[0], inWt[1], xz[0], xz[1], res[0], res[1], DM, DM);
  conv_k<<<dim3((M_*64)/256, 1, 2), 256, 0, stream>>>(
      xz[0], xz[1], convWt[0], convWt[1], convBc[0], convBc[1], xsc[0], xsc[1]);
  gemm_r_k<1,3,4,1,DI,0><<<dim3(M_/64, 1, 2), 256, 0, stream>>>(
      xsc[0], xsc[1], xWt[0], xWt[1], xdbl[0], xdbl[1], DI, DI, 48);

  if (newscan){
    dt_k<<<dim3(M_/32, 1, 2), 256, 0, stream>>>(
        xdbl[0], xdbl[1], dtWt[0], dtWt[1], dtBc[0], dtBc[1], dgA[0], dgA[1]);
    scanA_k<<<dim3(NC*2, B_, 2), 256, 0, stream>>>(
        xdbl[0], xdbl[1], xsc[0], xsc[1], dgA[0], dgA[1], ALf[0], ALf[1], hend, sumd);
    scanB_k<<<131072/256, 256, 0, stream>>>(ALf[0], ALf[1], hend, sumd, Hbuf);
    scanC_k<<<dim3(NC*2, B_, 2), 256, 0, stream>>>(
        xdbl[0], xdbl[1], xsc[0], xsc[1], res[0], res[1],
        dgA[0], dgA[1], ALf[0], ALf[1], Dpc[0], Dpc[1], Hbuf);
  } else {
    scan_k<<<dim3(DI/16, B_, 2), 256, 0, stream>>>(
        xdbl[0], xdbl[1], xsc[0], xsc[1], res[0], res[1], dtWt[0], dtWt[1],
        dtBc[0], dtBc[1], ALc[0], ALc[1], Dpc[0], Dpc[1]);
  }

  // final fused GEMM: out = yg_f@BtC0^T + flip(yg_b)@BtC1^T + fusB + x
  gemm_fin_k<64,64,DI><<<dim3(M_/64, DM/64, 1), 256, 0, stream>>>(
      res[0], res[1], BtC[0], BtC[1], d_out, fusBc, d_in[0], flag);
}